// Round 16
// baseline (347.985 us; speedup 1.0000x reference)
//
#include <hip/hip_runtime.h>
#include <math.h>

#define N_USER 24000
#define N_ITEM 8000
#define N_NODE 32000
#define N_EDGE 800000
#define NJC    16          // j-chunks for sim/topk
#define JCH    512         // j per chunk = 32 tiles of 16 (last chunk masked)

typedef __attribute__((ext_vector_type(8))) short bf16x8;
typedef __attribute__((ext_vector_type(4))) float f32x4;

__device__ __forceinline__ float wred_sum(float v) {
#pragma unroll
  for (int off = 32; off; off >>= 1) v += __shfl_xor(v, off, 64);
  return v;
}

__device__ __forceinline__ unsigned short f2bf(float f) {
  unsigned int u = __float_as_uint(f);
  unsigned int r = (u + 0x7fffu + ((u >> 16) & 1u)) >> 16;
  return (unsigned short)r;
}
__device__ __forceinline__ float bf2f(unsigned short h) {
  return __uint_as_float(((unsigned int)h) << 16);
}

__device__ __forceinline__ unsigned int umx(unsigned int a, unsigned int b) { return a > b ? a : b; }
__device__ __forceinline__ unsigned int umn(unsigned int a, unsigned int b) { return a < b ? a : b; }
// single-instruction median-of-3 (V_MED3_U32, gfx9 lineage)
__device__ __forceinline__ unsigned int umed3(unsigned int a, unsigned int b, unsigned int c) {
  unsigned int d;
  asm("v_med3_u32 %0, %1, %2, %3" : "=v"(d) : "v"(a), "v"(b), "v"(c));
  return d;
}

// key encode: v19 = trunc(sim*131072 + 131080) in [0, 2^19); key = (v19<<13) | (8191-j)
__device__ __forceinline__ float key_val(unsigned int k) {
  return ((float)(int)(k >> 13) - 131080.0f) * (1.0f / 131072.0f);
}
__device__ __forceinline__ int key_idx(unsigned int k) {
  return 8191 - (int)(k & 8191u);
}

// ============ L1: dual projection MFMA-GEMM (378 blocks) + ui_count (3125) ===
#define NB_G 378
__global__ __launch_bounds__(256) void k_gemm_count(
    const float* __restrict__ Xi, const float* __restrict__ Wi,
    const float* __restrict__ Xt, const float* __restrict__ Wt,
    float* __restrict__ Pi, float* __restrict__ Pt,
    const int* __restrict__ r, int* __restrict__ degi)
{
  __shared__ char lds2[24576];   // XH 8K | XL 8K | WH 4K | WL 4K
  char* ldsXH = lds2;
  char* ldsXL = lds2 + 8192;
  char* ldsWH = lds2 + 16384;
  char* ldsWL = lds2 + 20480;
  const int tid = threadIdx.x;
  const int b = blockIdx.x;
  if (b >= NB_G) {                         // ---- ui_count path ----
    int e = (b - NB_G) * 256 + tid;        // 3125*256 == 800000 exactly
    atomicAdd(&degi[r[e]], 1);
    return;
  }
  const int m0 = (b % 63) * 128;
  const int cy = b / 63;
  const float* X; const float* W; float* out; int K, kc0, ksteps;
  if (cy < 4) { X = Xi; W = Wi; K = 2048; kc0 = cy * 512; ksteps = 16;
                out = Pi + (size_t)cy * N_ITEM * 64; }
  else        { X = Xt; W = Wt; K = 384;  kc0 = (cy - 4) * 192; ksteps = 6;
                out = Pt + (size_t)(cy - 4) * N_ITEM * 64; }
  const int l = tid & 63;
  const int wid = tid >> 6;
  f32x4 acc[2][4] = {};

  for (int ks = 0; ks < ksteps; ++ks) {
    int k0 = kc0 + ks * 32;
    __syncthreads();
#pragma unroll
    for (int lq = 0; lq < 4; ++lq) {
      int u = tid + lq * 256;              // 0..1023
      int rr = u >> 3, q = u & 7;
      int grow = m0 + rr; if (grow > N_ITEM - 1) grow = N_ITEM - 1;
      float4 xv = *(const float4*)(X + (size_t)grow * K + k0 + q * 4);
      unsigned short h0 = f2bf(xv.x), h1 = f2bf(xv.y), h2 = f2bf(xv.z), h3 = f2bf(xv.w);
      unsigned int hA = ((unsigned int)h1 << 16) | h0;
      unsigned int hB = ((unsigned int)h3 << 16) | h2;
      unsigned short l0 = f2bf(xv.x - bf2f(h0)), l1 = f2bf(xv.y - bf2f(h1));
      unsigned short l2 = f2bf(xv.z - bf2f(h2)), l3 = f2bf(xv.w - bf2f(h3));
      unsigned int lA = ((unsigned int)l1 << 16) | l0;
      unsigned int lB = ((unsigned int)l3 << 16) | l2;
      int slot = q >> 1;
      int bo = rr * 64 + ((slot ^ ((rr >> 1) & 3)) << 4) + (q & 1) * 8;
      *(int2*)(ldsXH + bo) = make_int2((int)hA, (int)hB);
      *(int2*)(ldsXL + bo) = make_int2((int)lA, (int)lB);
    }
#pragma unroll
    for (int lq = 0; lq < 2; ++lq) {
      int u = tid + lq * 256;              // 0..511
      int kb = u >> 4, nq = (u & 15) * 4;
      float4 wv = *(const float4*)(W + (size_t)(k0 + kb) * 64 + nq);
      int slot = kb >> 3, within = kb & 7;
      float wa[4] = {wv.x, wv.y, wv.z, wv.w};
#pragma unroll
      for (int j = 0; j < 4; ++j) {
        int n = nq + j;
        unsigned short h = f2bf(wa[j]);
        unsigned short lo = f2bf(wa[j] - bf2f(h));
        int bo = n * 64 + ((slot ^ ((n >> 1) & 3)) << 4) + within * 2;
        *(unsigned short*)(ldsWH + bo) = h;
        *(unsigned short*)(ldsWL + bo) = lo;
      }
    }
    __syncthreads();
    bf16x8 xh[2], xl[2], wh[4], wl[4];
    int slot = l >> 4;
#pragma unroll
    for (int s = 0; s < 2; ++s) {
      int rr = wid * 32 + s * 16 + (l & 15);
      int bo = rr * 64 + ((slot ^ ((rr >> 1) & 3)) << 4);
      xh[s] = *(const bf16x8*)(ldsXH + bo);
      xl[s] = *(const bf16x8*)(ldsXL + bo);
    }
#pragma unroll
    for (int nt = 0; nt < 4; ++nt) {
      int n = nt * 16 + (l & 15);
      int bo = n * 64 + ((slot ^ ((n >> 1) & 3)) << 4);
      wh[nt] = *(const bf16x8*)(ldsWH + bo);
      wl[nt] = *(const bf16x8*)(ldsWL + bo);
    }
#pragma unroll
    for (int s = 0; s < 2; ++s)
#pragma unroll
      for (int nt = 0; nt < 4; ++nt) {
        acc[s][nt] = __builtin_amdgcn_mfma_f32_16x16x32_bf16(xh[s], wh[nt], acc[s][nt], 0, 0, 0);
        acc[s][nt] = __builtin_amdgcn_mfma_f32_16x16x32_bf16(xh[s], wl[nt], acc[s][nt], 0, 0, 0);
        acc[s][nt] = __builtin_amdgcn_mfma_f32_16x16x32_bf16(xl[s], wh[nt], acc[s][nt], 0, 0, 0);
      }
  }
#pragma unroll
  for (int s = 0; s < 2; ++s)
#pragma unroll
    for (int nt = 0; nt < 4; ++nt)
#pragma unroll
      for (int r4 = 0; r4 < 4; ++r4) {
        int gi = m0 + wid * 32 + s * 16 + ((l >> 4) << 2) + r4;
        int gn = nt * 16 + (l & 15);
        if (gi < N_ITEM) out[(size_t)gi * 64 + gn] = acc[s][nt][r4];
      }
}

// ============ L2: sum partials + bias, L2-normalize, split bf16 ==============
__global__ __launch_bounds__(256) void norm_dual(
    const float* __restrict__ Pi, const float* __restrict__ bi,
    unsigned short* __restrict__ Xhi, unsigned short* __restrict__ Xli,
    const float* __restrict__ Pt, const float* __restrict__ bt,
    unsigned short* __restrict__ Xht, unsigned short* __restrict__ Xlt)
{
  const float* P; const float* bias; unsigned short *Xh, *Xl; int nk;
  if (blockIdx.y == 0) { P = Pi; bias = bi; Xh = Xhi; Xl = Xli; nk = 4; }
  else                 { P = Pt; bias = bt; Xh = Xht; Xl = Xlt; nk = 2; }
  int row = blockIdx.x * 4 + (threadIdx.x >> 6);
  int lane = threadIdx.x & 63;
  size_t o = (size_t)row * 64 + lane;
  float v = bias[lane];
  for (int q = 0; q < nk; ++q) v += P[(size_t)q * N_ITEM * 64 + o];
  float ss = wred_sum(v * v);
  float xn = v * rsqrtf(ss);
  unsigned short hi = f2bf(xn);
  Xh[o] = hi;
  Xl[o] = f2bf(xn - bf2f(hi));
}

// ============ L3: block 0 = hierarchical scan; blocks 1.. = MFMA sim+topk ====
// sim: NO LDS staging — A-fragments read directly from global (Xh/Xl are
// 2 MB/modality, fully L2-resident). No __syncthreads -> waves independent,
// occupancy limited only by VGPRs.
#define NB_SIM 2016        // 63 x 16 x 2
__global__ __launch_bounds__(256) void k_sim_scan(
    const unsigned short* __restrict__ Xhi, const unsigned short* __restrict__ Xli,
    const unsigned short* __restrict__ Xht, const unsigned short* __restrict__ Xlt,
    unsigned int* __restrict__ pk,
    const int* __restrict__ degi, int* __restrict__ offs, float* __restrict__ disui)
{
  __shared__ int sbuf[1024];               // 4 KiB, scan path only
  const int tid = threadIdx.x;

  if (blockIdx.x == 0) {                   // ---- 3-phase block-local scan ----
    int* stot  = sbuf;                     // 500 chunk totals
    int* sbase = sbuf + 512;               // 500 chunk exclusive bases
    int lane = tid & 63, w = tid >> 6;
    for (int k = 0; k < 125; ++k) {
      int c = w * 125 + k;
      int d = degi[c * 64 + lane];
      int s = d;
#pragma unroll
      for (int off = 32; off; off >>= 1) s += __shfl_xor(s, off, 64);
      if (lane == 0) stot[c] = s;
    }
    __syncthreads();
    if (w == 0) {
      int run = 0;
      for (int r = 0; r < 8; ++r) {
        int idx = r * 64 + lane;
        int v = (idx < 500) ? stot[idx] : 0;
        int p = v;
#pragma unroll
        for (int off = 1; off < 64; off <<= 1) {
          int n = __shfl_up(p, off, 64);
          if (lane >= off) p += n;
        }
        if (idx < 500) sbase[idx] = run + p - v;
        run += __shfl(p, 63, 64);
      }
    }
    __syncthreads();
    for (int k = 0; k < 125; ++k) {
      int c = w * 125 + k;
      int i = c * 64 + lane;
      int d = degi[i];
      int p = d;
#pragma unroll
      for (int off = 1; off < 64; off <<= 1) {
        int n = __shfl_up(p, off, 64);
        if (lane >= off) p += n;
      }
      offs[i] = sbase[c] + p - d;
      disui[i] = d > 0 ? rsqrtf((float)d) : 0.f;
    }
    if (tid == 0) offs[N_NODE] = N_EDGE;   // total degree == edge count
    return;
  }

  // ---- sim path ----
  const int b = blockIdx.x - 1;
  const int bz = b / 1008;
  const int rem = b % 1008;
  const int by = rem / 63;
  const int bx = rem % 63;
  const unsigned short* Xh = bz ? Xht : Xhi;
  const unsigned short* Xl = bz ? Xlt : Xli;
  unsigned int* pkm = pk + (size_t)bz * N_ITEM * (NJC * 10);

  const int l = tid & 63;
  const int wid = tid >> 6;
  const int ib = bx * 128 + wid * 32;
  const int jc = by * JCH;
  const bool lastc = (jc + JCH > N_ITEM);

  // B-fragments (i side), loaded once
  bf16x8 bh[2][2], bl[2][2];
#pragma unroll
  for (int s = 0; s < 2; ++s) {
    int irow = ib + s * 16 + (l & 15);
    if (irow > N_ITEM - 1) irow = N_ITEM - 1;
    int ksl = (l >> 4) * 8;
#pragma unroll
    for (int kh = 0; kh < 2; ++kh) {
      bh[s][kh] = *(const bf16x8*)(Xh + (size_t)irow * 64 + kh * 32 + ksl);
      bl[s][kh] = *(const bf16x8*)(Xl + (size_t)irow * 64 + kh * 32 + ksl);
    }
  }

  unsigned int K0[10], K1[10];
#pragma unroll
  for (int t = 0; t < 10; ++t) { K0[t] = 0u; K1[t] = 0u; }

  // A-fragment loader: lane l = row (l&15), k-slice (l>>4)*8 (64B-coalesced)
  const int arow = l & 15;
  const int aksl = (l >> 4) * 8;
  auto loadA = [&](int tp, bf16x8& h0, bf16x8& h1, bf16x8& lo0, bf16x8& lo1) {
    int jr = jc + tp * 16 + arow;
    if (jr > N_ITEM - 1) jr = N_ITEM - 1;
    size_t base = (size_t)jr * 64 + aksl;
    h0  = *(const bf16x8*)(Xh + base);
    h1  = *(const bf16x8*)(Xh + base + 32);
    lo0 = *(const bf16x8*)(Xl + base);
    lo1 = *(const bf16x8*)(Xl + base + 32);
  };

// branchless epilogue: med3 insertion over one tile (4 values per list)
#define EPI4(MASKED)                                                           \
  _Pragma("unroll")                                                            \
  for (int s = 0; s < 2; ++s) {                                                \
    unsigned int* K = s ? K1 : K0;                                             \
    _Pragma("unroll")                                                          \
    for (int r = 0; r < 4; ++r) {                                              \
      float f = acc[s][r];                                                     \
      unsigned int v19 = (unsigned int)(int)(f * 131072.0f + 131080.0f);       \
      unsigned int key = (v19 << 13) | (unsigned int)jinv[r];                  \
      if (MASKED) key = (jinv[r] >= 192) ? key : 0u;                           \
      _Pragma("unroll")                                                        \
      for (int q = 9; q >= 1; --q) K[q] = umed3(K[q - 1], K[q], key);          \
      K[0] = umx(K[0], key);                                                   \
    }                                                                          \
  }

  bf16x8 ah0, ah1, al0, al1;
  loadA(0, ah0, ah1, al0, al1);
  for (int tp = 0; tp < 32; ++tp) {        // 32 j-tiles of 16
    bf16x8 nh0, nh1, nl0, nl1;
    if (tp < 31) loadA(tp + 1, nh0, nh1, nl0, nl1);   // prefetch next tile
    f32x4 acc[2] = {};
#pragma unroll
    for (int s = 0; s < 2; ++s) {
      acc[s] = __builtin_amdgcn_mfma_f32_16x16x32_bf16(ah0, bh[s][0], acc[s], 0, 0, 0);
      acc[s] = __builtin_amdgcn_mfma_f32_16x16x32_bf16(ah1, bh[s][1], acc[s], 0, 0, 0);
      acc[s] = __builtin_amdgcn_mfma_f32_16x16x32_bf16(ah0, bl[s][0], acc[s], 0, 0, 0);
      acc[s] = __builtin_amdgcn_mfma_f32_16x16x32_bf16(ah1, bl[s][1], acc[s], 0, 0, 0);
      acc[s] = __builtin_amdgcn_mfma_f32_16x16x32_bf16(al0, bh[s][0], acc[s], 0, 0, 0);
      acc[s] = __builtin_amdgcn_mfma_f32_16x16x32_bf16(al1, bh[s][1], acc[s], 0, 0, 0);
    }
    const int jg0 = jc + tp * 16 + ((l >> 4) << 2);
    int jinv[4];
#pragma unroll
    for (int r = 0; r < 4; ++r) jinv[r] = 8191 - (jg0 + r);
    if (!lastc) { EPI4(false) } else { EPI4(true) }
    ah0 = nh0; ah1 = nh1; al0 = nl0; al1 = nl1;
  }
#undef EPI4

  // in-wave merge of 4 lane-groups (shfl 16/32 tournament), lanes 0..15 store
#pragma unroll
  for (int s = 0; s < 2; ++s) {
    unsigned int* K = s ? K1 : K0;
    unsigned int kv[10];
#pragma unroll
    for (int t = 0; t < 10; ++t) {
      unsigned int m = K[0];
      m = umx(m, (unsigned int)__shfl_xor((int)m, 16, 64));
      m = umx(m, (unsigned int)__shfl_xor((int)m, 32, 64));
      bool own = (K[0] == m);
#pragma unroll
      for (int q2 = 0; q2 < 9; ++q2) K[q2] = own ? K[q2 + 1] : K[q2];
      K[9] = own ? 0u : K[9];
      kv[t] = m;
    }
    int i = ib + s * 16 + (l & 15);
    if (l < 16 && i < N_ITEM) {
      size_t base = ((size_t)i * NJC + by) * 10;
#pragma unroll
      for (int t = 0; t < 10; ++t) pkm[base + t] = kv[t];
    }
  }
}

// ============ L4: merge topk (4000 blocks) + ui_fill (3125) ==================
#define NB_M 4000
__global__ __launch_bounds__(256) void k_merge_fill(
    const unsigned int* __restrict__ pk,
    float* __restrict__ tv_i, int* __restrict__ tc_i, float* __restrict__ dis_i,
    float* __restrict__ tv_t, int* __restrict__ tc_t, float* __restrict__ dis_t,
    const int* __restrict__ r, const int* __restrict__ c,
    const int* __restrict__ offs, int* __restrict__ cursor, int* __restrict__ csr)
{
  int b = blockIdx.x;
  int tid = threadIdx.x;
  if (b >= NB_M) {                         // ---- ui_fill path ----
    int e = (b - NB_M) * 256 + tid;
    int rr = r[e];
    int pos = offs[rr] + atomicAdd(&cursor[rr], 1);
    csr[pos] = c[e];
    return;
  }
  int my = b / 2000, mx = b % 2000;
  float* tv; int* tc; float* dis;
  if (my == 0) { tv = tv_i; tc = tc_i; dis = dis_i; }
  else         { tv = tv_t; tc = tc_t; dis = dis_t; }
  int lane = tid & 63;
  int row = mx * 4 + (tid >> 6);
  size_t base = (size_t)my * N_ITEM * (NJC * 10) + (size_t)row * (NJC * 10);
  unsigned int k0 = pk[base + lane];
  unsigned int k1 = pk[base + 64 + lane];
  unsigned int k2 = (lane < 32) ? pk[base + 128 + lane] : 0u;
  float deg = 0.f, keepv = 0.f; int keepc = 0;
  for (int t = 0; t < 10; ++t) {
    unsigned int m = umx(umx(k0, k1), k2);
#pragma unroll
    for (int off = 32; off; off >>= 1)
      m = umx(m, (unsigned int)__shfl_xor((int)m, off, 64));
    deg += key_val(m);
    if (k0 == m) k0 = 0u;
    else if (k1 == m) k1 = 0u;
    else if (k2 == m) k2 = 0u;
    if (lane == t) { keepv = key_val(m); keepc = key_idx(m); }
  }
  if (lane < 10) { tv[(size_t)row * 10 + lane] = keepv; tc[(size_t)row * 10 + lane] = keepc; }
  if (lane == 0) dis[row] = deg > 0.f ? rsqrtf(deg) : 0.f;
}

// ============ L5: spmm+attn+hnorm (2000 blocks) + ui_prop layer1 (8000) ======
#define NB_S 2000
__global__ __launch_bounds__(256) void k_spmm_prop1(
    const float* __restrict__ tv_i, const int* __restrict__ tc_i, const float* __restrict__ dis_i,
    const float* __restrict__ ow_i, const int* __restrict__ oc_i,
    const float* __restrict__ tv_t, const int* __restrict__ tc_t, const float* __restrict__ dis_t,
    const float* __restrict__ ow_t, const int* __restrict__ oc_t,
    const float* __restrict__ item_emb,
    const float* __restrict__ Wq1, const float* __restrict__ bq1,
    const float* __restrict__ wq2, float* __restrict__ hn,
    const float* __restrict__ ue, float* __restrict__ E1,
    const int* __restrict__ offs, const int* __restrict__ csr,
    const float* __restrict__ dis)
{
  __shared__ float Wlds[64 * 64];
  __shared__ float sm[4][2][64];
  int tid = threadIdx.x;
  int lane = tid & 63, wid = tid >> 6;
  int b = blockIdx.x;
  if (b >= NB_S) {                         // ---- ui_prop layer-1 path ----
    int row = (b - NB_S) * 4 + wid;
    int q = lane >> 3, c8 = lane & 7;
    float4 acc0 = make_float4(0.f, 0.f, 0.f, 0.f);
    float4 acc1 = make_float4(0.f, 0.f, 0.f, 0.f);
    int e0 = offs[row], e1 = offs[row + 1];
    for (int e = e0 + q; e < e1; e += 8) {
      int cc = csr[e];
      const float* src = cc < N_USER ? ue + (size_t)cc * 64
                                     : item_emb + (size_t)(cc - N_USER) * 64;
      float4 v0 = *(const float4*)(src + c8 * 8);
      float4 v1 = *(const float4*)(src + c8 * 8 + 4);
      float d = dis[cc];
      acc0.x += d * v0.x; acc0.y += d * v0.y; acc0.z += d * v0.z; acc0.w += d * v0.w;
      acc1.x += d * v1.x; acc1.y += d * v1.y; acc1.z += d * v1.z; acc1.w += d * v1.w;
    }
#pragma unroll
    for (int off = 8; off <= 32; off <<= 1) {
      acc0.x += __shfl_xor(acc0.x, off, 64);
      acc0.y += __shfl_xor(acc0.y, off, 64);
      acc0.z += __shfl_xor(acc0.z, off, 64);
      acc0.w += __shfl_xor(acc0.w, off, 64);
      acc1.x += __shfl_xor(acc1.x, off, 64);
      acc1.y += __shfl_xor(acc1.y, off, 64);
      acc1.z += __shfl_xor(acc1.z, off, 64);
      acc1.w += __shfl_xor(acc1.w, off, 64);
    }
    if (q == 0) {
      float dr = dis[row];
      acc0.x *= dr; acc0.y *= dr; acc0.z *= dr; acc0.w *= dr;
      acc1.x *= dr; acc1.y *= dr; acc1.z *= dr; acc1.w *= dr;
      *(float4*)(E1 + (size_t)row * 64 + c8 * 8) = acc0;
      *(float4*)(E1 + (size_t)row * 64 + c8 * 8 + 4) = acc1;
    }
    return;
  }
  // ---- spmm + attention + h_norm path ----
  int row = b * 4 + wid;
#pragma unroll
  for (int s = 0; s < 4; ++s) {
    int idx = tid + s * 256;
    ((float4*)Wlds)[idx] = ((const float4*)Wq1)[idx];
  }
  float a0 = 0.f, a1 = 0.f;
  {
    float disr = dis_i[row];
#pragma unroll
    for (int t = 0; t < 10; ++t) {
      int c = tc_i[(size_t)row * 10 + t];
      a0 += 0.1f * disr * tv_i[(size_t)row * 10 + t] * dis_i[c] * item_emb[(size_t)c * 64 + lane];
    }
#pragma unroll
    for (int t = 0; t < 10; ++t) {
      int c = oc_i[(size_t)row * 10 + t];
      a0 += 0.9f * ow_i[(size_t)row * 10 + t] * item_emb[(size_t)c * 64 + lane];
    }
  }
  {
    float disr = dis_t[row];
#pragma unroll
    for (int t = 0; t < 10; ++t) {
      int c = tc_t[(size_t)row * 10 + t];
      a1 += 0.1f * disr * tv_t[(size_t)row * 10 + t] * dis_t[c] * item_emb[(size_t)c * 64 + lane];
    }
#pragma unroll
    for (int t = 0; t < 10; ++t) {
      int c = oc_t[(size_t)row * 10 + t];
      a1 += 0.9f * ow_t[(size_t)row * 10 + t] * item_emb[(size_t)c * 64 + lane];
    }
  }
  sm[wid][0][lane] = a0;
  sm[wid][1][lane] = a1;
  __syncthreads();
  float y0 = bq1[lane], y1 = bq1[lane];
  for (int k = 0; k < 64; ++k) {
    float w = Wlds[k * 64 + lane];
    y0 += sm[wid][0][k] * w;
    y1 += sm[wid][1][k] * w;
  }
  float wq = wq2[lane];
  float s0 = wred_sum(tanhf(y0) * wq);
  float s1 = wred_sum(tanhf(y1) * wq);
  float mx = fmaxf(s0, s1);
  float e0 = expf(s0 - mx), e1 = expf(s1 - mx);
  float inv = 1.f / (e0 + e1);
  float h = (e0 * inv) * a0 + (e1 * inv) * a1;
  float n2 = wred_sum(h * h);
  float nrm = fmaxf(sqrtf(n2), 1e-12f);
  hn[(size_t)row * 64 + lane] = h / nrm;
}

// ============ L6: ui_prop layer2 + mean + h add (final) ======================
__global__ __launch_bounds__(256) void k_prop2(
    const float* __restrict__ in, const float* __restrict__ ue,
    const float* __restrict__ ie, float* __restrict__ out,
    const int* __restrict__ offs, const int* __restrict__ csr,
    const float* __restrict__ dis, const float* __restrict__ hn)
{
  int tid = threadIdx.x;
  int lane = tid & 63, wid = tid >> 6;
  int row = blockIdx.x * 4 + wid;
  int q = lane >> 3, c8 = lane & 7;
  float4 acc0 = make_float4(0.f, 0.f, 0.f, 0.f);
  float4 acc1 = make_float4(0.f, 0.f, 0.f, 0.f);
  int e0 = offs[row], e1 = offs[row + 1];
  for (int e = e0 + q; e < e1; e += 8) {
    int cc = csr[e];
    const float* src = in + (size_t)cc * 64;
    float4 v0 = *(const float4*)(src + c8 * 8);
    float4 v1 = *(const float4*)(src + c8 * 8 + 4);
    float d = dis[cc];
    acc0.x += d * v0.x; acc0.y += d * v0.y; acc0.z += d * v0.z; acc0.w += d * v0.w;
    acc1.x += d * v1.x; acc1.y += d * v1.y; acc1.z += d * v1.z; acc1.w += d * v1.w;
  }
#pragma unroll
  for (int off = 8; off <= 32; off <<= 1) {
    acc0.x += __shfl_xor(acc0.x, off, 64);
    acc0.y += __shfl_xor(acc0.y, off, 64);
    acc0.z += __shfl_xor(acc0.z, off, 64);
    acc0.w += __shfl_xor(acc0.w, off, 64);
    acc1.x += __shfl_xor(acc1.x, off, 64);
    acc1.y += __shfl_xor(acc1.y, off, 64);
    acc1.z += __shfl_xor(acc1.z, off, 64);
    acc1.w += __shfl_xor(acc1.w, off, 64);
  }
  if (q == 0) {
    float dr = dis[row];
    acc0.x *= dr; acc0.y *= dr; acc0.z *= dr; acc0.w *= dr;
    acc1.x *= dr; acc1.y *= dr; acc1.z *= dr; acc1.w *= dr;
    const float* egop = (row < N_USER) ? ue + (size_t)row * 64
                                       : ie + (size_t)(row - N_USER) * 64;
    float4 eg0 = *(const float4*)(egop + c8 * 8);
    float4 eg1 = *(const float4*)(egop + c8 * 8 + 4);
    float4 l10 = *(const float4*)(in + (size_t)row * 64 + c8 * 8);
    float4 l11 = *(const float4*)(in + (size_t)row * 64 + c8 * 8 + 4);
    float4 o0, o1;
    o0.x = (eg0.x + l10.x + acc0.x) * (1.f / 3.f);
    o0.y = (eg0.y + l10.y + acc0.y) * (1.f / 3.f);
    o0.z = (eg0.z + l10.z + acc0.z) * (1.f / 3.f);
    o0.w = (eg0.w + l10.w + acc0.w) * (1.f / 3.f);
    o1.x = (eg1.x + l11.x + acc1.x) * (1.f / 3.f);
    o1.y = (eg1.y + l11.y + acc1.y) * (1.f / 3.f);
    o1.z = (eg1.z + l11.z + acc1.z) * (1.f / 3.f);
    o1.w = (eg1.w + l11.w + acc1.w) * (1.f / 3.f);
    if (row >= N_USER) {
      const float* hp = hn + (size_t)(row - N_USER) * 64;
      float4 h0 = *(const float4*)(hp + c8 * 8);
      float4 h1 = *(const float4*)(hp + c8 * 8 + 4);
      o0.x += h0.x; o0.y += h0.y; o0.z += h0.z; o0.w += h0.w;
      o1.x += h1.x; o1.y += h1.y; o1.z += h1.z; o1.w += h1.w;
    }
    *(float4*)(out + (size_t)row * 64 + c8 * 8) = o0;
    *(float4*)(out + (size_t)row * 64 + c8 * 8 + 4) = o1;
  }
}

// ---------------- host driver ------------------------------------------------
extern "C" void kernel_launch(void* const* d_in, const int* in_sizes, int n_in,
                              void* d_out, int out_size, void* d_ws, size_t ws_size,
                              hipStream_t stream)
{
  (void)in_sizes; (void)n_in; (void)out_size; (void)ws_size;
  const float* user_emb = (const float*)d_in[0];
  const float* item_emb = (const float*)d_in[1];
  const float* v_feat   = (const float*)d_in[2];
  const float* t_feat   = (const float*)d_in[3];
  const float* W_v      = (const float*)d_in[4];
  const float* b_v      = (const float*)d_in[5];
  const float* W_t      = (const float*)d_in[6];
  const float* b_t      = (const float*)d_in[7];
  const float* Wq1      = (const float*)d_in[8];
  const float* bq1      = (const float*)d_in[9];
  const float* wq2      = (const float*)d_in[10];
  const float* ow_i     = (const float*)d_in[11];
  const float* ow_t     = (const float*)d_in[12];
  const int*   eidx     = (const int*)d_in[13];
  const int*   oc_i     = (const int*)d_in[14];
  const int*   oc_t     = (const int*)d_in[15];
  float* out = (float*)d_out;

  char* wp = (char*)d_ws;
  auto alloc = [&](size_t bytes) -> void* {
    void* p = (void*)wp;
    wp += (bytes + 255) & ~(size_t)255;
    return p;
  };
  // region A: Pp_i (4 x 2.05 MB) -> later pk (2 x 5.12 MB = 10.24 MB)
  size_t pk_bytes = (size_t)2 * N_ITEM * (NJC * 10) * 4;          // 10.24 MB
  char* regionA = (char*)alloc(pk_bytes + 1024);
  // region B: Pp_t (2 x 2.05 MB) -> later E1 (8.19 MB)
  char* regionB = (char*)alloc((size_t)N_NODE * 64 * 4 + 1024);
  float* Pp_i = (float*)regionA;
  float* Pp_t = (float*)regionB;
  unsigned int* pk = (unsigned int*)regionA;    // alive after norm_dual
  float* E1 = (float*)regionB;                  // alive after L3 (sim reads done)

  unsigned short* Xhi = (unsigned short*)alloc((size_t)N_ITEM * 64 * 2);
  unsigned short* Xli = (unsigned short*)alloc((size_t)N_ITEM * 64 * 2);
  unsigned short* Xht = (unsigned short*)alloc((size_t)N_ITEM * 64 * 2);
  unsigned short* Xlt = (unsigned short*)alloc((size_t)N_ITEM * 64 * 2);
  float* tv_i  = (float*)alloc((size_t)N_ITEM * 10 * 4);
  int*   tc_i  = (int*)  alloc((size_t)N_ITEM * 10 * 4);
  float* dis_i = (float*)alloc((size_t)N_ITEM * 4);
  float* tv_t  = (float*)alloc((size_t)N_ITEM * 10 * 4);
  int*   tc_t  = (int*)  alloc((size_t)N_ITEM * 10 * 4);
  float* dis_t = (float*)alloc((size_t)N_ITEM * 4);
  float* hn    = (float*)alloc((size_t)N_ITEM * 64 * 4);
  int*   degcur= (int*)  alloc((size_t)2 * N_NODE * 4);   // degi | curs contiguous
  int*   degi  = degcur;
  int*   curs  = degcur + N_NODE;
  int*   offs  = (int*)  alloc((size_t)(N_NODE + 1) * 4);
  float* disui = (float*)alloc((size_t)N_NODE * 4);
  int*   csr   = (int*)  alloc((size_t)N_EDGE * 4);

  // L0: zero degree + cursor arrays (single async memset, capture-safe)
  hipMemsetAsync(degcur, 0, (size_t)2 * N_NODE * 4, stream);
  // L1: MFMA projections (both modalities) + UI degree count
  k_gemm_count<<<NB_G + 3125, 256, 0, stream>>>(v_feat, W_v, t_feat, W_t, Pp_i, Pp_t,
                                                eidx, degi);
  // L2: normalize + bf16 hi/lo split
  norm_dual<<<dim3(2000, 2), 256, 0, stream>>>(Pp_i, b_v, Xhi, Xli, Pp_t, b_t, Xht, Xlt);
  // L3: scan (block 0, overlapped) + sim + topk (both modalities)
  k_sim_scan<<<NB_SIM + 1, 256, 0, stream>>>(Xhi, Xli, Xht, Xlt, pk, degi, offs, disui);
  // L4: merge candidates -> top10/dis + CSR fill
  k_merge_fill<<<NB_M + 3125, 256, 0, stream>>>(pk, tv_i, tc_i, dis_i, tv_t, tc_t, dis_t,
                                                eidx, eidx + N_EDGE, offs, curs, csr);
  // L5: fused SPMM+attention+h_norm + UI propagation layer 1
  k_spmm_prop1<<<NB_S + 8000, 256, 0, stream>>>(tv_i, tc_i, dis_i, ow_i, oc_i,
                                                tv_t, tc_t, dis_t, ow_t, oc_t,
                                                item_emb, Wq1, bq1, wq2, hn,
                                                user_emb, E1, offs, csr, disui);
  // L6: UI propagation layer 2 + mean + h_norm add
  k_prop2<<<8000, 256, 0, stream>>>(E1, user_emb, item_emb, out, offs, csr, disui, hn);
}

// Round 17
// 300.365 us; speedup vs baseline: 1.1585x; 1.1585x over previous
//
#include <hip/hip_runtime.h>
#include <math.h>

#define N_USER 24000
#define N_ITEM 8000
#define N_NODE 32000
#define N_EDGE 800000
#define NJC    16          // j-chunks for sim/topk
#define JCH    512         // j per chunk = 16 panels of 32 (last chunk masked)

typedef __attribute__((ext_vector_type(8))) short bf16x8;
typedef __attribute__((ext_vector_type(4))) float f32x4;

__device__ __forceinline__ float wred_sum(float v) {
#pragma unroll
  for (int off = 32; off; off >>= 1) v += __shfl_xor(v, off, 64);
  return v;
}

__device__ __forceinline__ unsigned short f2bf(float f) {
  unsigned int u = __float_as_uint(f);
  unsigned int r = (u + 0x7fffu + ((u >> 16) & 1u)) >> 16;
  return (unsigned short)r;
}
__device__ __forceinline__ float bf2f(unsigned short h) {
  return __uint_as_float(((unsigned int)h) << 16);
}

__device__ __forceinline__ unsigned int umx(unsigned int a, unsigned int b) { return a > b ? a : b; }
__device__ __forceinline__ unsigned int umn(unsigned int a, unsigned int b) { return a < b ? a : b; }
// single-instruction median-of-3 (V_MED3_U32, gfx9 lineage)
__device__ __forceinline__ unsigned int umed3(unsigned int a, unsigned int b, unsigned int c) {
  unsigned int d;
  asm("v_med3_u32 %0, %1, %2, %3" : "=v"(d) : "v"(a), "v"(b), "v"(c));
  return d;
}

// key encode: v19 = trunc(sim*131072 + 131080) in [0, 2^19); key = (v19<<13) | (8191-j)
__device__ __forceinline__ float key_val(unsigned int k) {
  return ((float)(int)(k >> 13) - 131080.0f) * (1.0f / 131072.0f);
}
__device__ __forceinline__ int key_idx(unsigned int k) {
  return 8191 - (int)(k & 8191u);
}

// ============ L1: dual projection MFMA-GEMM (378 blocks) + ui_count (3125) ===
#define NB_G 378
__global__ __launch_bounds__(256) void k_gemm_count(
    const float* __restrict__ Xi, const float* __restrict__ Wi,
    const float* __restrict__ Xt, const float* __restrict__ Wt,
    float* __restrict__ Pi, float* __restrict__ Pt,
    const int* __restrict__ r, int* __restrict__ degi)
{
  __shared__ char lds2[24576];   // XH 8K | XL 8K | WH 4K | WL 4K
  char* ldsXH = lds2;
  char* ldsXL = lds2 + 8192;
  char* ldsWH = lds2 + 16384;
  char* ldsWL = lds2 + 20480;
  const int tid = threadIdx.x;
  const int b = blockIdx.x;
  if (b >= NB_G) {                         // ---- ui_count path ----
    int e = (b - NB_G) * 256 + tid;        // 3125*256 == 800000 exactly
    atomicAdd(&degi[r[e]], 1);
    return;
  }
  const int m0 = (b % 63) * 128;
  const int cy = b / 63;
  const float* X; const float* W; float* out; int K, kc0, ksteps;
  if (cy < 4) { X = Xi; W = Wi; K = 2048; kc0 = cy * 512; ksteps = 16;
                out = Pi + (size_t)cy * N_ITEM * 64; }
  else        { X = Xt; W = Wt; K = 384;  kc0 = (cy - 4) * 192; ksteps = 6;
                out = Pt + (size_t)(cy - 4) * N_ITEM * 64; }
  const int l = tid & 63;
  const int wid = tid >> 6;
  f32x4 acc[2][4] = {};

  for (int ks = 0; ks < ksteps; ++ks) {
    int k0 = kc0 + ks * 32;
    __syncthreads();
#pragma unroll
    for (int lq = 0; lq < 4; ++lq) {
      int u = tid + lq * 256;              // 0..1023
      int rr = u >> 3, q = u & 7;
      int grow = m0 + rr; if (grow > N_ITEM - 1) grow = N_ITEM - 1;
      float4 xv = *(const float4*)(X + (size_t)grow * K + k0 + q * 4);
      unsigned short h0 = f2bf(xv.x), h1 = f2bf(xv.y), h2 = f2bf(xv.z), h3 = f2bf(xv.w);
      unsigned int hA = ((unsigned int)h1 << 16) | h0;
      unsigned int hB = ((unsigned int)h3 << 16) | h2;
      unsigned short l0 = f2bf(xv.x - bf2f(h0)), l1 = f2bf(xv.y - bf2f(h1));
      unsigned short l2 = f2bf(xv.z - bf2f(h2)), l3 = f2bf(xv.w - bf2f(h3));
      unsigned int lA = ((unsigned int)l1 << 16) | l0;
      unsigned int lB = ((unsigned int)l3 << 16) | l2;
      int slot = q >> 1;
      int bo = rr * 64 + ((slot ^ ((rr >> 1) & 3)) << 4) + (q & 1) * 8;
      *(int2*)(ldsXH + bo) = make_int2((int)hA, (int)hB);
      *(int2*)(ldsXL + bo) = make_int2((int)lA, (int)lB);
    }
#pragma unroll
    for (int lq = 0; lq < 2; ++lq) {
      int u = tid + lq * 256;              // 0..511
      int kb = u >> 4, nq = (u & 15) * 4;
      float4 wv = *(const float4*)(W + (size_t)(k0 + kb) * 64 + nq);
      int slot = kb >> 3, within = kb & 7;
      float wa[4] = {wv.x, wv.y, wv.z, wv.w};
#pragma unroll
      for (int j = 0; j < 4; ++j) {
        int n = nq + j;
        unsigned short h = f2bf(wa[j]);
        unsigned short lo = f2bf(wa[j] - bf2f(h));
        int bo = n * 64 + ((slot ^ ((n >> 1) & 3)) << 4) + within * 2;
        *(unsigned short*)(ldsWH + bo) = h;
        *(unsigned short*)(ldsWL + bo) = lo;
      }
    }
    __syncthreads();
    bf16x8 xh[2], xl[2], wh[4], wl[4];
    int slot = l >> 4;
#pragma unroll
    for (int s = 0; s < 2; ++s) {
      int rr = wid * 32 + s * 16 + (l & 15);
      int bo = rr * 64 + ((slot ^ ((rr >> 1) & 3)) << 4);
      xh[s] = *(const bf16x8*)(ldsXH + bo);
      xl[s] = *(const bf16x8*)(ldsXL + bo);
    }
#pragma unroll
    for (int nt = 0; nt < 4; ++nt) {
      int n = nt * 16 + (l & 15);
      int bo = n * 64 + ((slot ^ ((n >> 1) & 3)) << 4);
      wh[nt] = *(const bf16x8*)(ldsWH + bo);
      wl[nt] = *(const bf16x8*)(ldsWL + bo);
    }
#pragma unroll
    for (int s = 0; s < 2; ++s)
#pragma unroll
      for (int nt = 0; nt < 4; ++nt) {
        acc[s][nt] = __builtin_amdgcn_mfma_f32_16x16x32_bf16(xh[s], wh[nt], acc[s][nt], 0, 0, 0);
        acc[s][nt] = __builtin_amdgcn_mfma_f32_16x16x32_bf16(xh[s], wl[nt], acc[s][nt], 0, 0, 0);
        acc[s][nt] = __builtin_amdgcn_mfma_f32_16x16x32_bf16(xl[s], wh[nt], acc[s][nt], 0, 0, 0);
      }
  }
#pragma unroll
  for (int s = 0; s < 2; ++s)
#pragma unroll
    for (int nt = 0; nt < 4; ++nt)
#pragma unroll
      for (int r4 = 0; r4 < 4; ++r4) {
        int gi = m0 + wid * 32 + s * 16 + ((l >> 4) << 2) + r4;
        int gn = nt * 16 + (l & 15);
        if (gi < N_ITEM) out[(size_t)gi * 64 + gn] = acc[s][nt][r4];
      }
}

// ============ L2: sum partials + bias, L2-normalize, split bf16 ==============
__global__ __launch_bounds__(256) void norm_dual(
    const float* __restrict__ Pi, const float* __restrict__ bi,
    unsigned short* __restrict__ Xhi, unsigned short* __restrict__ Xli,
    const float* __restrict__ Pt, const float* __restrict__ bt,
    unsigned short* __restrict__ Xht, unsigned short* __restrict__ Xlt)
{
  const float* P; const float* bias; unsigned short *Xh, *Xl; int nk;
  if (blockIdx.y == 0) { P = Pi; bias = bi; Xh = Xhi; Xl = Xli; nk = 4; }
  else                 { P = Pt; bias = bt; Xh = Xht; Xl = Xlt; nk = 2; }
  int row = blockIdx.x * 4 + (threadIdx.x >> 6);
  int lane = threadIdx.x & 63;
  size_t o = (size_t)row * 64 + lane;
  float v = bias[lane];
  for (int q = 0; q < nk; ++q) v += P[(size_t)q * N_ITEM * 64 + o];
  float ss = wred_sum(v * v);
  float xn = v * rsqrtf(ss);
  unsigned short hi = f2bf(xn);
  Xh[o] = hi;
  Xl[o] = f2bf(xn - bf2f(hi));
}

// ============ L3: block 0 = hierarchical scan; blocks 1.. = MFMA sim+topk ====
#define NB_SIM 2016        // 63 x 16 x 2
__global__ __launch_bounds__(256) void k_sim_scan(
    const unsigned short* __restrict__ Xhi, const unsigned short* __restrict__ Xli,
    const unsigned short* __restrict__ Xht, const unsigned short* __restrict__ Xlt,
    unsigned int* __restrict__ pk,
    const int* __restrict__ degi, int* __restrict__ offs, float* __restrict__ disui)
{
  __shared__ char lds[2 * 2 * 32 * 128];   // 16 KiB (sim path; scan reuses 4 KiB)
  const int tid = threadIdx.x;

  if (blockIdx.x == 0) {                   // ---- 3-phase block-local scan ----
    int* stot  = (int*)lds;                // 500 chunk totals
    int* sbase = (int*)lds + 512;          // 500 chunk exclusive bases
    int lane = tid & 63, w = tid >> 6;
    for (int k = 0; k < 125; ++k) {
      int c = w * 125 + k;
      int d = degi[c * 64 + lane];
      int s = d;
#pragma unroll
      for (int off = 32; off; off >>= 1) s += __shfl_xor(s, off, 64);
      if (lane == 0) stot[c] = s;
    }
    __syncthreads();
    if (w == 0) {
      int run = 0;
      for (int r = 0; r < 8; ++r) {
        int idx = r * 64 + lane;
        int v = (idx < 500) ? stot[idx] : 0;
        int p = v;
#pragma unroll
        for (int off = 1; off < 64; off <<= 1) {
          int n = __shfl_up(p, off, 64);
          if (lane >= off) p += n;
        }
        if (idx < 500) sbase[idx] = run + p - v;
        run += __shfl(p, 63, 64);
      }
    }
    __syncthreads();
    for (int k = 0; k < 125; ++k) {
      int c = w * 125 + k;
      int i = c * 64 + lane;
      int d = degi[i];
      int p = d;
#pragma unroll
      for (int off = 1; off < 64; off <<= 1) {
        int n = __shfl_up(p, off, 64);
        if (lane >= off) p += n;
      }
      offs[i] = sbase[c] + p - d;
      disui[i] = d > 0 ? rsqrtf((float)d) : 0.f;
    }
    if (tid == 0) offs[N_NODE] = N_EDGE;   // total degree == edge count
    return;
  }

  // ---- sim path ----
  const int b = blockIdx.x - 1;
  const int bz = b / 1008;
  const int rem = b % 1008;
  const int by = rem / 63;
  const int bx = rem % 63;
  const unsigned short* Xh = bz ? Xht : Xhi;
  const unsigned short* Xl = bz ? Xlt : Xli;
  unsigned int* pkm = pk + (size_t)bz * N_ITEM * (NJC * 10);

  const int l = tid & 63;
  const int wid = tid >> 6;
  const int ib = bx * 128 + wid * 32;
  const int jc = by * JCH;
  const bool lastc = (jc + JCH > N_ITEM);

  bf16x8 bh[2][2], bl[2][2];
#pragma unroll
  for (int s = 0; s < 2; ++s) {
    int irow = ib + s * 16 + (l & 15);
    if (irow > N_ITEM - 1) irow = N_ITEM - 1;
    int ksl = (l >> 4) * 8;
#pragma unroll
    for (int kh = 0; kh < 2; ++kh) {
      bh[s][kh] = *(const bf16x8*)(Xh + (size_t)irow * 64 + kh * 32 + ksl);
      bl[s][kh] = *(const bf16x8*)(Xl + (size_t)irow * 64 + kh * 32 + ksl);
    }
  }

  unsigned int K0[10], K1[10];
#pragma unroll
  for (int t = 0; t < 10; ++t) { K0[t] = 0u; K1[t] = 0u; }

  auto stage = [&](int bb, int p) {
    int row = tid >> 3, cb = (tid & 7) * 16;
    int gr = jc + p * 32 + row;
    if (gr > N_ITEM - 1) gr = N_ITEM - 1;
    int4 vh = *(const int4*)(Xh + (size_t)gr * 64 + (cb >> 1));
    int4 vl = *(const int4*)(Xl + (size_t)gr * 64 + (cb >> 1));
    int bo = (row * 128 + cb) ^ ((row & 7) << 4);
    *(int4*)(lds + bb * 8192 + bo) = vh;
    *(int4*)(lds + bb * 8192 + 4096 + bo) = vl;
  };

// branchless epilogue: med3 insertion (K desc-sorted; all med3 independent)
#define EPI(MASKED)                                                            \
  _Pragma("unroll")                                                            \
  for (int s = 0; s < 2; ++s) {                                                \
    unsigned int* K = s ? K1 : K0;                                             \
    _Pragma("unroll")                                                          \
    for (int t = 0; t < 2; ++t) {                                              \
      _Pragma("unroll")                                                        \
      for (int r = 0; r < 4; ++r) {                                            \
        float f = acc[t][s][r];                                                \
        unsigned int v19 = (unsigned int)(int)(f * 131072.0f + 131080.0f);     \
        unsigned int key = (v19 << 13) | (unsigned int)jinv[t * 4 + r];        \
        if (MASKED) key = (jinv[t * 4 + r] >= 192) ? key : 0u;                 \
        _Pragma("unroll")                                                      \
        for (int q = 9; q >= 1; --q) K[q] = umed3(K[q - 1], K[q], key);        \
        K[0] = umx(K[0], key);                                                 \
      }                                                                        \
    }                                                                          \
  }

  stage(0, 0);
  int cur = 0;
  for (int p = 0; p < 16; ++p) {
    __syncthreads();
    if (p < 15) stage(cur ^ 1, p + 1);
    const char* ldsH = lds + cur * 8192;
    const char* ldsL = ldsH + 4096;
    f32x4 acc[2][2] = {};
#pragma unroll
    for (int t = 0; t < 2; ++t) {
      int jr = t * 16 + (l & 15);
      int sw = (jr & 7) << 4;
      int rb = jr * 128 + ((l >> 4) << 4);
      bf16x8 ah0 = *(const bf16x8*)(ldsH + (rb ^ sw));
      bf16x8 ah1 = *(const bf16x8*)(ldsH + ((rb + 64) ^ sw));
      bf16x8 al0 = *(const bf16x8*)(ldsL + (rb ^ sw));
      bf16x8 al1 = *(const bf16x8*)(ldsL + ((rb + 64) ^ sw));
#pragma unroll
      for (int s = 0; s < 2; ++s) {
        acc[t][s] = __builtin_amdgcn_mfma_f32_16x16x32_bf16(ah0, bh[s][0], acc[t][s], 0, 0, 0);
        acc[t][s] = __builtin_amdgcn_mfma_f32_16x16x32_bf16(ah1, bh[s][1], acc[t][s], 0, 0, 0);
        acc[t][s] = __builtin_amdgcn_mfma_f32_16x16x32_bf16(ah0, bl[s][0], acc[t][s], 0, 0, 0);
        acc[t][s] = __builtin_amdgcn_mfma_f32_16x16x32_bf16(ah1, bl[s][1], acc[t][s], 0, 0, 0);
        acc[t][s] = __builtin_amdgcn_mfma_f32_16x16x32_bf16(al0, bh[s][0], acc[t][s], 0, 0, 0);
        acc[t][s] = __builtin_amdgcn_mfma_f32_16x16x32_bf16(al1, bh[s][1], acc[t][s], 0, 0, 0);
      }
    }
    const int jg0 = jc + p * 32 + ((l >> 4) << 2);
    int jinv[8];
#pragma unroll
    for (int t = 0; t < 2; ++t)
#pragma unroll
      for (int r = 0; r < 4; ++r)
        jinv[t * 4 + r] = 8191 - (jg0 + t * 16 + r);
    if (!lastc) { EPI(false) } else { EPI(true) }
    cur ^= 1;
  }
#undef EPI

#pragma unroll
  for (int s = 0; s < 2; ++s) {
    unsigned int* K = s ? K1 : K0;
    unsigned int kv[10];
#pragma unroll
    for (int t = 0; t < 10; ++t) {
      unsigned int m = K[0];
      m = umx(m, (unsigned int)__shfl_xor((int)m, 16, 64));
      m = umx(m, (unsigned int)__shfl_xor((int)m, 32, 64));
      bool own = (K[0] == m);
#pragma unroll
      for (int q2 = 0; q2 < 9; ++q2) K[q2] = own ? K[q2 + 1] : K[q2];
      K[9] = own ? 0u : K[9];
      kv[t] = m;
    }
    int i = ib + s * 16 + (l & 15);
    if (l < 16 && i < N_ITEM) {
      size_t base = ((size_t)i * NJC + by) * 10;
#pragma unroll
      for (int t = 0; t < 10; ++t) pkm[base + t] = kv[t];
    }
  }
}

// ============ L4: merge topk (4000 blocks) + ui_fill (3125) ==================
#define NB_M 4000
__global__ __launch_bounds__(256) void k_merge_fill(
    const unsigned int* __restrict__ pk,
    float* __restrict__ tv_i, int* __restrict__ tc_i, float* __restrict__ dis_i,
    float* __restrict__ tv_t, int* __restrict__ tc_t, float* __restrict__ dis_t,
    const int* __restrict__ r, const int* __restrict__ c,
    const int* __restrict__ offs, int* __restrict__ cursor, int* __restrict__ csr)
{
  int b = blockIdx.x;
  int tid = threadIdx.x;
  if (b >= NB_M) {                         // ---- ui_fill path ----
    int e = (b - NB_M) * 256 + tid;
    int rr = r[e];
    int pos = offs[rr] + atomicAdd(&cursor[rr], 1);
    csr[pos] = c[e];
    return;
  }
  int my = b / 2000, mx = b % 2000;
  float* tv; int* tc; float* dis;
  if (my == 0) { tv = tv_i; tc = tc_i; dis = dis_i; }
  else         { tv = tv_t; tc = tc_t; dis = dis_t; }
  int lane = tid & 63;
  int row = mx * 4 + (tid >> 6);
  size_t base = (size_t)my * N_ITEM * (NJC * 10) + (size_t)row * (NJC * 10);
  unsigned int k0 = pk[base + lane];
  unsigned int k1 = pk[base + 64 + lane];
  unsigned int k2 = (lane < 32) ? pk[base + 128 + lane] : 0u;
  float deg = 0.f, keepv = 0.f; int keepc = 0;
  for (int t = 0; t < 10; ++t) {
    unsigned int m = umx(umx(k0, k1), k2);
#pragma unroll
    for (int off = 32; off; off >>= 1)
      m = umx(m, (unsigned int)__shfl_xor((int)m, off, 64));
    deg += key_val(m);
    if (k0 == m) k0 = 0u;
    else if (k1 == m) k1 = 0u;
    else if (k2 == m) k2 = 0u;
    if (lane == t) { keepv = key_val(m); keepc = key_idx(m); }
  }
  if (lane < 10) { tv[(size_t)row * 10 + lane] = keepv; tc[(size_t)row * 10 + lane] = keepc; }
  if (lane == 0) dis[row] = deg > 0.f ? rsqrtf(deg) : 0.f;
}

// ============ L5: spmm+attn+hnorm (2000 blocks) + ui_prop layer1 (8000) ======
#define NB_S 2000
__global__ __launch_bounds__(256) void k_spmm_prop1(
    const float* __restrict__ tv_i, const int* __restrict__ tc_i, const float* __restrict__ dis_i,
    const float* __restrict__ ow_i, const int* __restrict__ oc_i,
    const float* __restrict__ tv_t, const int* __restrict__ tc_t, const float* __restrict__ dis_t,
    const float* __restrict__ ow_t, const int* __restrict__ oc_t,
    const float* __restrict__ item_emb,
    const float* __restrict__ Wq1, const float* __restrict__ bq1,
    const float* __restrict__ wq2, float* __restrict__ hn,
    const float* __restrict__ ue, float* __restrict__ E1,
    const int* __restrict__ offs, const int* __restrict__ csr,
    const float* __restrict__ dis)
{
  __shared__ float Wlds[64 * 64];
  __shared__ float sm[4][2][64];
  int tid = threadIdx.x;
  int lane = tid & 63, wid = tid >> 6;
  int b = blockIdx.x;
  if (b >= NB_S) {                         // ---- ui_prop layer-1 path ----
    int row = (b - NB_S) * 4 + wid;
    int q = lane >> 3, c8 = lane & 7;
    float4 acc0 = make_float4(0.f, 0.f, 0.f, 0.f);
    float4 acc1 = make_float4(0.f, 0.f, 0.f, 0.f);
    int e0 = offs[row], e1 = offs[row + 1];
    for (int e = e0 + q; e < e1; e += 8) {
      int cc = csr[e];
      const float* src = cc < N_USER ? ue + (size_t)cc * 64
                                     : item_emb + (size_t)(cc - N_USER) * 64;
      float4 v0 = *(const float4*)(src + c8 * 8);
      float4 v1 = *(const float4*)(src + c8 * 8 + 4);
      float d = dis[cc];
      acc0.x += d * v0.x; acc0.y += d * v0.y; acc0.z += d * v0.z; acc0.w += d * v0.w;
      acc1.x += d * v1.x; acc1.y += d * v1.y; acc1.z += d * v1.z; acc1.w += d * v1.w;
    }
#pragma unroll
    for (int off = 8; off <= 32; off <<= 1) {
      acc0.x += __shfl_xor(acc0.x, off, 64);
      acc0.y += __shfl_xor(acc0.y, off, 64);
      acc0.z += __shfl_xor(acc0.z, off, 64);
      acc0.w += __shfl_xor(acc0.w, off, 64);
      acc1.x += __shfl_xor(acc1.x, off, 64);
      acc1.y += __shfl_xor(acc1.y, off, 64);
      acc1.z += __shfl_xor(acc1.z, off, 64);
      acc1.w += __shfl_xor(acc1.w, off, 64);
    }
    if (q == 0) {
      float dr = dis[row];
      acc0.x *= dr; acc0.y *= dr; acc0.z *= dr; acc0.w *= dr;
      acc1.x *= dr; acc1.y *= dr; acc1.z *= dr; acc1.w *= dr;
      *(float4*)(E1 + (size_t)row * 64 + c8 * 8) = acc0;
      *(float4*)(E1 + (size_t)row * 64 + c8 * 8 + 4) = acc1;
    }
    return;
  }
  // ---- spmm + attention + h_norm path ----
  int row = b * 4 + wid;
#pragma unroll
  for (int s = 0; s < 4; ++s) {
    int idx = tid + s * 256;
    ((float4*)Wlds)[idx] = ((const float4*)Wq1)[idx];
  }
  float a0 = 0.f, a1 = 0.f;
  {
    float disr = dis_i[row];
#pragma unroll
    for (int t = 0; t < 10; ++t) {
      int c = tc_i[(size_t)row * 10 + t];
      a0 += 0.1f * disr * tv_i[(size_t)row * 10 + t] * dis_i[c] * item_emb[(size_t)c * 64 + lane];
    }
#pragma unroll
    for (int t = 0; t < 10; ++t) {
      int c = oc_i[(size_t)row * 10 + t];
      a0 += 0.9f * ow_i[(size_t)row * 10 + t] * item_emb[(size_t)c * 64 + lane];
    }
  }
  {
    float disr = dis_t[row];
#pragma unroll
    for (int t = 0; t < 10; ++t) {
      int c = tc_t[(size_t)row * 10 + t];
      a1 += 0.1f * disr * tv_t[(size_t)row * 10 + t] * dis_t[c] * item_emb[(size_t)c * 64 + lane];
    }
#pragma unroll
    for (int t = 0; t < 10; ++t) {
      int c = oc_t[(size_t)row * 10 + t];
      a1 += 0.9f * ow_t[(size_t)row * 10 + t] * item_emb[(size_t)c * 64 + lane];
    }
  }
  sm[wid][0][lane] = a0;
  sm[wid][1][lane] = a1;
  __syncthreads();
  float y0 = bq1[lane], y1 = bq1[lane];
  for (int k = 0; k < 64; ++k) {
    float w = Wlds[k * 64 + lane];
    y0 += sm[wid][0][k] * w;
    y1 += sm[wid][1][k] * w;
  }
  float wq = wq2[lane];
  float s0 = wred_sum(tanhf(y0) * wq);
  float s1 = wred_sum(tanhf(y1) * wq);
  float mx = fmaxf(s0, s1);
  float e0 = expf(s0 - mx), e1 = expf(s1 - mx);
  float inv = 1.f / (e0 + e1);
  float h = (e0 * inv) * a0 + (e1 * inv) * a1;
  float n2 = wred_sum(h * h);
  float nrm = fmaxf(sqrtf(n2), 1e-12f);
  hn[(size_t)row * 64 + lane] = h / nrm;
}

// ============ L6: ui_prop layer2 + mean + h add (final) ======================
__global__ __launch_bounds__(256) void k_prop2(
    const float* __restrict__ in, const float* __restrict__ ue,
    const float* __restrict__ ie, float* __restrict__ out,
    const int* __restrict__ offs, const int* __restrict__ csr,
    const float* __restrict__ dis, const float* __restrict__ hn)
{
  int tid = threadIdx.x;
  int lane = tid & 63, wid = tid >> 6;
  int row = blockIdx.x * 4 + wid;
  int q = lane >> 3, c8 = lane & 7;
  float4 acc0 = make_float4(0.f, 0.f, 0.f, 0.f);
  float4 acc1 = make_float4(0.f, 0.f, 0.f, 0.f);
  int e0 = offs[row], e1 = offs[row + 1];
  for (int e = e0 + q; e < e1; e += 8) {
    int cc = csr[e];
    const float* src = in + (size_t)cc * 64;
    float4 v0 = *(const float4*)(src + c8 * 8);
    float4 v1 = *(const float4*)(src + c8 * 8 + 4);
    float d = dis[cc];
    acc0.x += d * v0.x; acc0.y += d * v0.y; acc0.z += d * v0.z; acc0.w += d * v0.w;
    acc1.x += d * v1.x; acc1.y += d * v1.y; acc1.z += d * v1.z; acc1.w += d * v1.w;
  }
#pragma unroll
  for (int off = 8; off <= 32; off <<= 1) {
    acc0.x += __shfl_xor(acc0.x, off, 64);
    acc0.y += __shfl_xor(acc0.y, off, 64);
    acc0.z += __shfl_xor(acc0.z, off, 64);
    acc0.w += __shfl_xor(acc0.w, off, 64);
    acc1.x += __shfl_xor(acc1.x, off, 64);
    acc1.y += __shfl_xor(acc1.y, off, 64);
    acc1.z += __shfl_xor(acc1.z, off, 64);
    acc1.w += __shfl_xor(acc1.w, off, 64);
  }
  if (q == 0) {
    float dr = dis[row];
    acc0.x *= dr; acc0.y *= dr; acc0.z *= dr; acc0.w *= dr;
    acc1.x *= dr; acc1.y *= dr; acc1.z *= dr; acc1.w *= dr;
    const float* egop = (row < N_USER) ? ue + (size_t)row * 64
                                       : ie + (size_t)(row - N_USER) * 64;
    float4 eg0 = *(const float4*)(egop + c8 * 8);
    float4 eg1 = *(const float4*)(egop + c8 * 8 + 4);
    float4 l10 = *(const float4*)(in + (size_t)row * 64 + c8 * 8);
    float4 l11 = *(const float4*)(in + (size_t)row * 64 + c8 * 8 + 4);
    float4 o0, o1;
    o0.x = (eg0.x + l10.x + acc0.x) * (1.f / 3.f);
    o0.y = (eg0.y + l10.y + acc0.y) * (1.f / 3.f);
    o0.z = (eg0.z + l10.z + acc0.z) * (1.f / 3.f);
    o0.w = (eg0.w + l10.w + acc0.w) * (1.f / 3.f);
    o1.x = (eg1.x + l11.x + acc1.x) * (1.f / 3.f);
    o1.y = (eg1.y + l11.y + acc1.y) * (1.f / 3.f);
    o1.z = (eg1.z + l11.z + acc1.z) * (1.f / 3.f);
    o1.w = (eg1.w + l11.w + acc1.w) * (1.f / 3.f);
    if (row >= N_USER) {
      const float* hp = hn + (size_t)(row - N_USER) * 64;
      float4 h0 = *(const float4*)(hp + c8 * 8);
      float4 h1 = *(const float4*)(hp + c8 * 8 + 4);
      o0.x += h0.x; o0.y += h0.y; o0.z += h0.z; o0.w += h0.w;
      o1.x += h1.x; o1.y += h1.y; o1.z += h1.z; o1.w += h1.w;
    }
    *(float4*)(out + (size_t)row * 64 + c8 * 8) = o0;
    *(float4*)(out + (size_t)row * 64 + c8 * 8 + 4) = o1;
  }
}

// ---------------- host driver ------------------------------------------------
extern "C" void kernel_launch(void* const* d_in, const int* in_sizes, int n_in,
                              void* d_out, int out_size, void* d_ws, size_t ws_size,
                              hipStream_t stream)
{
  (void)in_sizes; (void)n_in; (void)out_size; (void)ws_size;
  const float* user_emb = (const float*)d_in[0];
  const float* item_emb = (const float*)d_in[1];
  const float* v_feat   = (const float*)d_in[2];
  const float* t_feat   = (const float*)d_in[3];
  const float* W_v      = (const float*)d_in[4];
  const float* b_v      = (const float*)d_in[5];
  const float* W_t      = (const float*)d_in[6];
  const float* b_t      = (const float*)d_in[7];
  const float* Wq1      = (const float*)d_in[8];
  const float* bq1      = (const float*)d_in[9];
  const float* wq2      = (const float*)d_in[10];
  const float* ow_i     = (const float*)d_in[11];
  const float* ow_t     = (const float*)d_in[12];
  const int*   eidx     = (const int*)d_in[13];
  const int*   oc_i     = (const int*)d_in[14];
  const int*   oc_t     = (const int*)d_in[15];
  float* out = (float*)d_out;

  char* wp = (char*)d_ws;
  auto alloc = [&](size_t bytes) -> void* {
    void* p = (void*)wp;
    wp += (bytes + 255) & ~(size_t)255;
    return p;
  };
  // region A: Pp_i (4 x 2.05 MB) -> later pk (2 x 5.12 MB = 10.24 MB)
  size_t pk_bytes = (size_t)2 * N_ITEM * (NJC * 10) * 4;          // 10.24 MB
  char* regionA = (char*)alloc(pk_bytes + 1024);
  // region B: Pp_t (2 x 2.05 MB) -> later E1 (8.19 MB)
  char* regionB = (char*)alloc((size_t)N_NODE * 64 * 4 + 1024);
  float* Pp_i = (float*)regionA;
  float* Pp_t = (float*)regionB;
  unsigned int* pk = (unsigned int*)regionA;    // alive after norm_dual
  float* E1 = (float*)regionB;                  // alive after L3 (sim reads done)

  unsigned short* Xhi = (unsigned short*)alloc((size_t)N_ITEM * 64 * 2);
  unsigned short* Xli = (unsigned short*)alloc((size_t)N_ITEM * 64 * 2);
  unsigned short* Xht = (unsigned short*)alloc((size_t)N_ITEM * 64 * 2);
  unsigned short* Xlt = (unsigned short*)alloc((size_t)N_ITEM * 64 * 2);
  float* tv_i  = (float*)alloc((size_t)N_ITEM * 10 * 4);
  int*   tc_i  = (int*)  alloc((size_t)N_ITEM * 10 * 4);
  float* dis_i = (float*)alloc((size_t)N_ITEM * 4);
  float* tv_t  = (float*)alloc((size_t)N_ITEM * 10 * 4);
  int*   tc_t  = (int*)  alloc((size_t)N_ITEM * 10 * 4);
  float* dis_t = (float*)alloc((size_t)N_ITEM * 4);
  float* hn    = (float*)alloc((size_t)N_ITEM * 64 * 4);
  int*   degcur= (int*)  alloc((size_t)2 * N_NODE * 4);   // degi | curs contiguous
  int*   degi  = degcur;
  int*   curs  = degcur + N_NODE;
  int*   offs  = (int*)  alloc((size_t)(N_NODE + 1) * 4);
  float* disui = (float*)alloc((size_t)N_NODE * 4);
  int*   csr   = (int*)  alloc((size_t)N_EDGE * 4);

  // L0: zero degree + cursor arrays (single async memset, capture-safe)
  hipMemsetAsync(degcur, 0, (size_t)2 * N_NODE * 4, stream);
  // L1: MFMA projections (both modalities) + UI degree count
  k_gemm_count<<<NB_G + 3125, 256, 0, stream>>>(v_feat, W_v, t_feat, W_t, Pp_i, Pp_t,
                                                eidx, degi);
  // L2: normalize + bf16 hi/lo split
  norm_dual<<<dim3(2000, 2), 256, 0, stream>>>(Pp_i, b_v, Xhi, Xli, Pp_t, b_t, Xht, Xlt);
  // L3: scan (block 0, overlapped) + sim + topk (both modalities)
  k_sim_scan<<<NB_SIM + 1, 256, 0, stream>>>(Xhi, Xli, Xht, Xlt, pk, degi, offs, disui);
  // L4: merge candidates -> top10/dis + CSR fill
  k_merge_fill<<<NB_M + 3125, 256, 0, stream>>>(pk, tv_i, tc_i, dis_i, tv_t, tc_t, dis_t,
                                                eidx, eidx + N_EDGE, offs, curs, csr);
  // L5: fused SPMM+attention+h_norm + UI propagation layer 1
  k_spmm_prop1<<<NB_S + 8000, 256, 0, stream>>>(tv_i, tc_i, dis_i, ow_i, oc_i,
                                                tv_t, tc_t, dis_t, ow_t, oc_t,
                                                item_emb, Wq1, bq1, wq2, hn,
                                                user_emb, E1, offs, csr, disui);
  // L6: UI propagation layer 2 + mean + h_norm add
  k_prop2<<<8000, 256, 0, stream>>>(E1, user_emb, item_emb, out, offs, csr, disui, hn);
}

// Round 18
// 300.214 us; speedup vs baseline: 1.1591x; 1.0005x over previous
//
#include <hip/hip_runtime.h>
#include <math.h>

#define N_USER 24000
#define N_ITEM 8000
#define N_NODE 32000
#define N_EDGE 800000
#define NJC    16          // j-chunks for sim/topk
#define JCH    512         // j per chunk = 8 panels of 64 (last chunk masked)

typedef __attribute__((ext_vector_type(8))) short bf16x8;
typedef __attribute__((ext_vector_type(4))) float f32x4;

__device__ __forceinline__ float wred_sum(float v) {
#pragma unroll
  for (int off = 32; off; off >>= 1) v += __shfl_xor(v, off, 64);
  return v;
}

__device__ __forceinline__ unsigned short f2bf(float f) {
  unsigned int u = __float_as_uint(f);
  unsigned int r = (u + 0x7fffu + ((u >> 16) & 1u)) >> 16;
  return (unsigned short)r;
}
__device__ __forceinline__ float bf2f(unsigned short h) {
  return __uint_as_float(((unsigned int)h) << 16);
}

__device__ __forceinline__ unsigned int umx(unsigned int a, unsigned int b) { return a > b ? a : b; }
__device__ __forceinline__ unsigned int umn(unsigned int a, unsigned int b) { return a < b ? a : b; }
// single-instruction median-of-3 (V_MED3_U32, gfx9 lineage)
__device__ __forceinline__ unsigned int umed3(unsigned int a, unsigned int b, unsigned int c) {
  unsigned int d;
  asm("v_med3_u32 %0, %1, %2, %3" : "=v"(d) : "v"(a), "v"(b), "v"(c));
  return d;
}

// key encode: v19 = trunc(sim*131072 + 131080) in [0, 2^19); key = (v19<<13) | (8191-j)
__device__ __forceinline__ float key_val(unsigned int k) {
  return ((float)(int)(k >> 13) - 131080.0f) * (1.0f / 131072.0f);
}
__device__ __forceinline__ int key_idx(unsigned int k) {
  return 8191 - (int)(k & 8191u);
}

// ============ L1: dual projection MFMA-GEMM (378 blocks) + ui_count (3125) ===
#define NB_G 378
__global__ __launch_bounds__(256) void k_gemm_count(
    const float* __restrict__ Xi, const float* __restrict__ Wi,
    const float* __restrict__ Xt, const float* __restrict__ Wt,
    float* __restrict__ Pi, float* __restrict__ Pt,
    const int* __restrict__ r, int* __restrict__ degi)
{
  __shared__ char lds2[24576];   // XH 8K | XL 8K | WH 4K | WL 4K
  char* ldsXH = lds2;
  char* ldsXL = lds2 + 8192;
  char* ldsWH = lds2 + 16384;
  char* ldsWL = lds2 + 20480;
  const int tid = threadIdx.x;
  const int b = blockIdx.x;
  if (b >= NB_G) {                         // ---- ui_count path ----
    int e = (b - NB_G) * 256 + tid;        // 3125*256 == 800000 exactly
    atomicAdd(&degi[r[e]], 1);
    return;
  }
  const int m0 = (b % 63) * 128;
  const int cy = b / 63;
  const float* X; const float* W; float* out; int K, kc0, ksteps;
  if (cy < 4) { X = Xi; W = Wi; K = 2048; kc0 = cy * 512; ksteps = 16;
                out = Pi + (size_t)cy * N_ITEM * 64; }
  else        { X = Xt; W = Wt; K = 384;  kc0 = (cy - 4) * 192; ksteps = 6;
                out = Pt + (size_t)(cy - 4) * N_ITEM * 64; }
  const int l = tid & 63;
  const int wid = tid >> 6;
  f32x4 acc[2][4] = {};

  for (int ks = 0; ks < ksteps; ++ks) {
    int k0 = kc0 + ks * 32;
    __syncthreads();
#pragma unroll
    for (int lq = 0; lq < 4; ++lq) {
      int u = tid + lq * 256;              // 0..1023
      int rr = u >> 3, q = u & 7;
      int grow = m0 + rr; if (grow > N_ITEM - 1) grow = N_ITEM - 1;
      float4 xv = *(const float4*)(X + (size_t)grow * K + k0 + q * 4);
      unsigned short h0 = f2bf(xv.x), h1 = f2bf(xv.y), h2 = f2bf(xv.z), h3 = f2bf(xv.w);
      unsigned int hA = ((unsigned int)h1 << 16) | h0;
      unsigned int hB = ((unsigned int)h3 << 16) | h2;
      unsigned short l0 = f2bf(xv.x - bf2f(h0)), l1 = f2bf(xv.y - bf2f(h1));
      unsigned short l2 = f2bf(xv.z - bf2f(h2)), l3 = f2bf(xv.w - bf2f(h3));
      unsigned int lA = ((unsigned int)l1 << 16) | l0;
      unsigned int lB = ((unsigned int)l3 << 16) | l2;
      int slot = q >> 1;
      int bo = rr * 64 + ((slot ^ ((rr >> 1) & 3)) << 4) + (q & 1) * 8;
      *(int2*)(ldsXH + bo) = make_int2((int)hA, (int)hB);
      *(int2*)(ldsXL + bo) = make_int2((int)lA, (int)lB);
    }
#pragma unroll
    for (int lq = 0; lq < 2; ++lq) {
      int u = tid + lq * 256;              // 0..511
      int kb = u >> 4, nq = (u & 15) * 4;
      float4 wv = *(const float4*)(W + (size_t)(k0 + kb) * 64 + nq);
      int slot = kb >> 3, within = kb & 7;
      float wa[4] = {wv.x, wv.y, wv.z, wv.w};
#pragma unroll
      for (int j = 0; j < 4; ++j) {
        int n = nq + j;
        unsigned short h = f2bf(wa[j]);
        unsigned short lo = f2bf(wa[j] - bf2f(h));
        int bo = n * 64 + ((slot ^ ((n >> 1) & 3)) << 4) + within * 2;
        *(unsigned short*)(ldsWH + bo) = h;
        *(unsigned short*)(ldsWL + bo) = lo;
      }
    }
    __syncthreads();
    bf16x8 xh[2], xl[2], wh[4], wl[4];
    int slot = l >> 4;
#pragma unroll
    for (int s = 0; s < 2; ++s) {
      int rr = wid * 32 + s * 16 + (l & 15);
      int bo = rr * 64 + ((slot ^ ((rr >> 1) & 3)) << 4);
      xh[s] = *(const bf16x8*)(ldsXH + bo);
      xl[s] = *(const bf16x8*)(ldsXL + bo);
    }
#pragma unroll
    for (int nt = 0; nt < 4; ++nt) {
      int n = nt * 16 + (l & 15);
      int bo = n * 64 + ((slot ^ ((n >> 1) & 3)) << 4);
      wh[nt] = *(const bf16x8*)(ldsWH + bo);
      wl[nt] = *(const bf16x8*)(ldsWL + bo);
    }
#pragma unroll
    for (int s = 0; s < 2; ++s)
#pragma unroll
      for (int nt = 0; nt < 4; ++nt) {
        acc[s][nt] = __builtin_amdgcn_mfma_f32_16x16x32_bf16(xh[s], wh[nt], acc[s][nt], 0, 0, 0);
        acc[s][nt] = __builtin_amdgcn_mfma_f32_16x16x32_bf16(xh[s], wl[nt], acc[s][nt], 0, 0, 0);
        acc[s][nt] = __builtin_amdgcn_mfma_f32_16x16x32_bf16(xl[s], wh[nt], acc[s][nt], 0, 0, 0);
      }
  }
#pragma unroll
  for (int s = 0; s < 2; ++s)
#pragma unroll
    for (int nt = 0; nt < 4; ++nt)
#pragma unroll
      for (int r4 = 0; r4 < 4; ++r4) {
        int gi = m0 + wid * 32 + s * 16 + ((l >> 4) << 2) + r4;
        int gn = nt * 16 + (l & 15);
        if (gi < N_ITEM) out[(size_t)gi * 64 + gn] = acc[s][nt][r4];
      }
}

// ============ L2: sum partials + bias, L2-normalize, split bf16 ==============
__global__ __launch_bounds__(256) void norm_dual(
    const float* __restrict__ Pi, const float* __restrict__ bi,
    unsigned short* __restrict__ Xhi, unsigned short* __restrict__ Xli,
    const float* __restrict__ Pt, const float* __restrict__ bt,
    unsigned short* __restrict__ Xht, unsigned short* __restrict__ Xlt)
{
  const float* P; const float* bias; unsigned short *Xh, *Xl; int nk;
  if (blockIdx.y == 0) { P = Pi; bias = bi; Xh = Xhi; Xl = Xli; nk = 4; }
  else                 { P = Pt; bias = bt; Xh = Xht; Xl = Xlt; nk = 2; }
  int row = blockIdx.x * 4 + (threadIdx.x >> 6);
  int lane = threadIdx.x & 63;
  size_t o = (size_t)row * 64 + lane;
  float v = bias[lane];
  for (int q = 0; q < nk; ++q) v += P[(size_t)q * N_ITEM * 64 + o];
  float ss = wred_sum(v * v);
  float xn = v * rsqrtf(ss);
  unsigned short hi = f2bf(xn);
  Xh[o] = hi;
  Xl[o] = f2bf(xn - bf2f(hi));
}

// ============ L3: block 0 = hierarchical scan; blocks 1.. = MFMA sim+topk ====
// 64-row panels (8 barriers instead of 16); LDS 32 KiB double-buffered.
#define NB_SIM 2016        // 63 x 16 x 2
__global__ __launch_bounds__(256) void k_sim_scan(
    const unsigned short* __restrict__ Xhi, const unsigned short* __restrict__ Xli,
    const unsigned short* __restrict__ Xht, const unsigned short* __restrict__ Xlt,
    unsigned int* __restrict__ pk,
    const int* __restrict__ degi, int* __restrict__ offs, float* __restrict__ disui)
{
  __shared__ char lds[2 * 2 * 64 * 128];   // 32 KiB (sim path; scan reuses 4 KiB)
  const int tid = threadIdx.x;

  if (blockIdx.x == 0) {                   // ---- 3-phase block-local scan ----
    int* stot  = (int*)lds;                // 500 chunk totals
    int* sbase = (int*)lds + 512;          // 500 chunk exclusive bases
    int lane = tid & 63, w = tid >> 6;
    for (int k = 0; k < 125; ++k) {
      int c = w * 125 + k;
      int d = degi[c * 64 + lane];
      int s = d;
#pragma unroll
      for (int off = 32; off; off >>= 1) s += __shfl_xor(s, off, 64);
      if (lane == 0) stot[c] = s;
    }
    __syncthreads();
    if (w == 0) {
      int run = 0;
      for (int r = 0; r < 8; ++r) {
        int idx = r * 64 + lane;
        int v = (idx < 500) ? stot[idx] : 0;
        int p = v;
#pragma unroll
        for (int off = 1; off < 64; off <<= 1) {
          int n = __shfl_up(p, off, 64);
          if (lane >= off) p += n;
        }
        if (idx < 500) sbase[idx] = run + p - v;
        run += __shfl(p, 63, 64);
      }
    }
    __syncthreads();
    for (int k = 0; k < 125; ++k) {
      int c = w * 125 + k;
      int i = c * 64 + lane;
      int d = degi[i];
      int p = d;
#pragma unroll
      for (int off = 1; off < 64; off <<= 1) {
        int n = __shfl_up(p, off, 64);
        if (lane >= off) p += n;
      }
      offs[i] = sbase[c] + p - d;
      disui[i] = d > 0 ? rsqrtf((float)d) : 0.f;
    }
    if (tid == 0) offs[N_NODE] = N_EDGE;   // total degree == edge count
    return;
  }

  // ---- sim path ----
  const int b = blockIdx.x - 1;
  const int bz = b / 1008;
  const int rem = b % 1008;
  const int by = rem / 63;
  const int bx = rem % 63;
  const unsigned short* Xh = bz ? Xht : Xhi;
  const unsigned short* Xl = bz ? Xlt : Xli;
  unsigned int* pkm = pk + (size_t)bz * N_ITEM * (NJC * 10);

  const int l = tid & 63;
  const int wid = tid >> 6;
  const int ib = bx * 128 + wid * 32;
  const int jc = by * JCH;
  const bool lastc = (jc + JCH > N_ITEM);

  bf16x8 bh[2][2], bl[2][2];
#pragma unroll
  for (int s = 0; s < 2; ++s) {
    int irow = ib + s * 16 + (l & 15);
    if (irow > N_ITEM - 1) irow = N_ITEM - 1;
    int ksl = (l >> 4) * 8;
#pragma unroll
    for (int kh = 0; kh < 2; ++kh) {
      bh[s][kh] = *(const bf16x8*)(Xh + (size_t)irow * 64 + kh * 32 + ksl);
      bl[s][kh] = *(const bf16x8*)(Xl + (size_t)irow * 64 + kh * 32 + ksl);
    }
  }

  unsigned int K0[10], K1[10];
#pragma unroll
  for (int t = 0; t < 10; ++t) { K0[t] = 0u; K1[t] = 0u; }

  // stage one 64-row panel (hi+lo): 512 16B-units per matrix, 2 per thread
  auto stage = [&](int bb, int p) {
#pragma unroll
    for (int s2 = 0; s2 < 2; ++s2) {
      int u = tid + s2 * 256;              // 0..511
      int row = u >> 3, cb = (u & 7) * 16;
      int gr = jc + p * 64 + row;
      if (gr > N_ITEM - 1) gr = N_ITEM - 1;
      int4 vh = *(const int4*)(Xh + (size_t)gr * 64 + (cb >> 1));
      int4 vl = *(const int4*)(Xl + (size_t)gr * 64 + (cb >> 1));
      int bo = (row * 128 + cb) ^ ((row & 7) << 4);
      *(int4*)(lds + bb * 16384 + bo) = vh;
      *(int4*)(lds + bb * 16384 + 8192 + bo) = vl;
    }
  };

// branchless epilogue: med3 insertion (K desc-sorted; all med3 independent)
#define EPI(MASKED)                                                            \
  _Pragma("unroll")                                                            \
  for (int s = 0; s < 2; ++s) {                                                \
    unsigned int* K = s ? K1 : K0;                                             \
    _Pragma("unroll")                                                          \
    for (int t = 0; t < 2; ++t) {                                              \
      _Pragma("unroll")                                                        \
      for (int r = 0; r < 4; ++r) {                                            \
        float f = acc[t][s][r];                                                \
        unsigned int v19 = (unsigned int)(int)(f * 131072.0f + 131080.0f);     \
        unsigned int key = (v19 << 13) | (unsigned int)jinv[t * 4 + r];        \
        if (MASKED) key = (jinv[t * 4 + r] >= 192) ? key : 0u;                 \
        _Pragma("unroll")                                                      \
        for (int q = 9; q >= 1; --q) K[q] = umed3(K[q - 1], K[q], key);        \
        K[0] = umx(K[0], key);                                                 \
      }                                                                        \
    }                                                                          \
  }

  stage(0, 0);
  int cur = 0;
  for (int p = 0; p < 8; ++p) {            // 8 panels of 64 rows
    __syncthreads();
    if (p < 7) stage(cur ^ 1, p + 1);
    const char* ldsH = lds + cur * 16384;
    const char* ldsL = ldsH + 8192;
#pragma unroll
    for (int half = 0; half < 2; ++half) { // two 32-row halves per panel
      f32x4 acc[2][2] = {};
#pragma unroll
      for (int t = 0; t < 2; ++t) {
        int jr = half * 32 + t * 16 + (l & 15);
        int sw = (jr & 7) << 4;
        int rb = jr * 128 + ((l >> 4) << 4);
        bf16x8 ah0 = *(const bf16x8*)(ldsH + (rb ^ sw));
        bf16x8 ah1 = *(const bf16x8*)(ldsH + ((rb + 64) ^ sw));
        bf16x8 al0 = *(const bf16x8*)(ldsL + (rb ^ sw));
        bf16x8 al1 = *(const bf16x8*)(ldsL + ((rb + 64) ^ sw));
#pragma unroll
        for (int s = 0; s < 2; ++s) {
          acc[t][s] = __builtin_amdgcn_mfma_f32_16x16x32_bf16(ah0, bh[s][0], acc[t][s], 0, 0, 0);
          acc[t][s] = __builtin_amdgcn_mfma_f32_16x16x32_bf16(ah1, bh[s][1], acc[t][s], 0, 0, 0);
          acc[t][s] = __builtin_amdgcn_mfma_f32_16x16x32_bf16(ah0, bl[s][0], acc[t][s], 0, 0, 0);
          acc[t][s] = __builtin_amdgcn_mfma_f32_16x16x32_bf16(ah1, bl[s][1], acc[t][s], 0, 0, 0);
          acc[t][s] = __builtin_amdgcn_mfma_f32_16x16x32_bf16(al0, bh[s][0], acc[t][s], 0, 0, 0);
          acc[t][s] = __builtin_amdgcn_mfma_f32_16x16x32_bf16(al1, bh[s][1], acc[t][s], 0, 0, 0);
        }
      }
      const int jg0 = jc + p * 64 + half * 32 + ((l >> 4) << 2);
      int jinv[8];
#pragma unroll
      for (int t = 0; t < 2; ++t)
#pragma unroll
        for (int r = 0; r < 4; ++r)
          jinv[t * 4 + r] = 8191 - (jg0 + t * 16 + r);
      if (!lastc) { EPI(false) } else { EPI(true) }
    }
    cur ^= 1;
  }
#undef EPI

#pragma unroll
  for (int s = 0; s < 2; ++s) {
    unsigned int* K = s ? K1 : K0;
    unsigned int kv[10];
#pragma unroll
    for (int t = 0; t < 10; ++t) {
      unsigned int m = K[0];
      m = umx(m, (unsigned int)__shfl_xor((int)m, 16, 64));
      m = umx(m, (unsigned int)__shfl_xor((int)m, 32, 64));
      bool own = (K[0] == m);
#pragma unroll
      for (int q2 = 0; q2 < 9; ++q2) K[q2] = own ? K[q2 + 1] : K[q2];
      K[9] = own ? 0u : K[9];
      kv[t] = m;
    }
    int i = ib + s * 16 + (l & 15);
    if (l < 16 && i < N_ITEM) {
      size_t base = ((size_t)i * NJC + by) * 10;
#pragma unroll
      for (int t = 0; t < 10; ++t) pkm[base + t] = kv[t];
    }
  }
}

// ============ L4: merge topk (4000 blocks) + ui_fill (3125) ==================
#define NB_M 4000
__global__ __launch_bounds__(256) void k_merge_fill(
    const unsigned int* __restrict__ pk,
    float* __restrict__ tv_i, int* __restrict__ tc_i, float* __restrict__ dis_i,
    float* __restrict__ tv_t, int* __restrict__ tc_t, float* __restrict__ dis_t,
    const int* __restrict__ r, const int* __restrict__ c,
    const int* __restrict__ offs, int* __restrict__ cursor, int* __restrict__ csr)
{
  int b = blockIdx.x;
  int tid = threadIdx.x;
  if (b >= NB_M) {                         // ---- ui_fill path ----
    int e = (b - NB_M) * 256 + tid;
    int rr = r[e];
    int pos = offs[rr] + atomicAdd(&cursor[rr], 1);
    csr[pos] = c[e];
    return;
  }
  int my = b / 2000, mx = b % 2000;
  float* tv; int* tc; float* dis;
  if (my == 0) { tv = tv_i; tc = tc_i; dis = dis_i; }
  else         { tv = tv_t; tc = tc_t; dis = dis_t; }
  int lane = tid & 63;
  int row = mx * 4 + (tid >> 6);
  size_t base = (size_t)my * N_ITEM * (NJC * 10) + (size_t)row * (NJC * 10);
  unsigned int k0 = pk[base + lane];
  unsigned int k1 = pk[base + 64 + lane];
  unsigned int k2 = (lane < 32) ? pk[base + 128 + lane] : 0u;
  float deg = 0.f, keepv = 0.f; int keepc = 0;
  for (int t = 0; t < 10; ++t) {
    unsigned int m = umx(umx(k0, k1), k2);
#pragma unroll
    for (int off = 32; off; off >>= 1)
      m = umx(m, (unsigned int)__shfl_xor((int)m, off, 64));
    deg += key_val(m);
    if (k0 == m) k0 = 0u;
    else if (k1 == m) k1 = 0u;
    else if (k2 == m) k2 = 0u;
    if (lane == t) { keepv = key_val(m); keepc = key_idx(m); }
  }
  if (lane < 10) { tv[(size_t)row * 10 + lane] = keepv; tc[(size_t)row * 10 + lane] = keepc; }
  if (lane == 0) dis[row] = deg > 0.f ? rsqrtf(deg) : 0.f;
}

// ============ L5: spmm+attn+hnorm (2000 blocks) + ui_prop layer1 (8000) ======
#define NB_S 2000
__global__ __launch_bounds__(256) void k_spmm_prop1(
    const float* __restrict__ tv_i, const int* __restrict__ tc_i, const float* __restrict__ dis_i,
    const float* __restrict__ ow_i, const int* __restrict__ oc_i,
    const float* __restrict__ tv_t, const int* __restrict__ tc_t, const float* __restrict__ dis_t,
    const float* __restrict__ ow_t, const int* __restrict__ oc_t,
    const float* __restrict__ item_emb,
    const float* __restrict__ Wq1, const float* __restrict__ bq1,
    const float* __restrict__ wq2, float* __restrict__ hn,
    const float* __restrict__ ue, float* __restrict__ E1,
    const int* __restrict__ offs, const int* __restrict__ csr,
    const float* __restrict__ dis)
{
  __shared__ float Wlds[64 * 64];
  __shared__ float sm[4][2][64];
  int tid = threadIdx.x;
  int lane = tid & 63, wid = tid >> 6;
  int b = blockIdx.x;
  if (b >= NB_S) {                         // ---- ui_prop layer-1 path ----
    int row = (b - NB_S) * 4 + wid;
    int q = lane >> 3, c8 = lane & 7;
    float4 acc0 = make_float4(0.f, 0.f, 0.f, 0.f);
    float4 acc1 = make_float4(0.f, 0.f, 0.f, 0.f);
    int e0 = offs[row], e1 = offs[row + 1];
    for (int e = e0 + q; e < e1; e += 8) {
      int cc = csr[e];
      const float* src = cc < N_USER ? ue + (size_t)cc * 64
                                     : item_emb + (size_t)(cc - N_USER) * 64;
      float4 v0 = *(const float4*)(src + c8 * 8);
      float4 v1 = *(const float4*)(src + c8 * 8 + 4);
      float d = dis[cc];
      acc0.x += d * v0.x; acc0.y += d * v0.y; acc0.z += d * v0.z; acc0.w += d * v0.w;
      acc1.x += d * v1.x; acc1.y += d * v1.y; acc1.z += d * v1.z; acc1.w += d * v1.w;
    }
#pragma unroll
    for (int off = 8; off <= 32; off <<= 1) {
      acc0.x += __shfl_xor(acc0.x, off, 64);
      acc0.y += __shfl_xor(acc0.y, off, 64);
      acc0.z += __shfl_xor(acc0.z, off, 64);
      acc0.w += __shfl_xor(acc0.w, off, 64);
      acc1.x += __shfl_xor(acc1.x, off, 64);
      acc1.y += __shfl_xor(acc1.y, off, 64);
      acc1.z += __shfl_xor(acc1.z, off, 64);
      acc1.w += __shfl_xor(acc1.w, off, 64);
    }
    if (q == 0) {
      float dr = dis[row];
      acc0.x *= dr; acc0.y *= dr; acc0.z *= dr; acc0.w *= dr;
      acc1.x *= dr; acc1.y *= dr; acc1.z *= dr; acc1.w *= dr;
      *(float4*)(E1 + (size_t)row * 64 + c8 * 8) = acc0;
      *(float4*)(E1 + (size_t)row * 64 + c8 * 8 + 4) = acc1;
    }
    return;
  }
  // ---- spmm + attention + h_norm path ----
  int row = b * 4 + wid;
#pragma unroll
  for (int s = 0; s < 4; ++s) {
    int idx = tid + s * 256;
    ((float4*)Wlds)[idx] = ((const float4*)Wq1)[idx];
  }
  float a0 = 0.f, a1 = 0.f;
  {
    float disr = dis_i[row];
#pragma unroll
    for (int t = 0; t < 10; ++t) {
      int c = tc_i[(size_t)row * 10 + t];
      a0 += 0.1f * disr * tv_i[(size_t)row * 10 + t] * dis_i[c] * item_emb[(size_t)c * 64 + lane];
    }
#pragma unroll
    for (int t = 0; t < 10; ++t) {
      int c = oc_i[(size_t)row * 10 + t];
      a0 += 0.9f * ow_i[(size_t)row * 10 + t] * item_emb[(size_t)c * 64 + lane];
    }
  }
  {
    float disr = dis_t[row];
#pragma unroll
    for (int t = 0; t < 10; ++t) {
      int c = tc_t[(size_t)row * 10 + t];
      a1 += 0.1f * disr * tv_t[(size_t)row * 10 + t] * dis_t[c] * item_emb[(size_t)c * 64 + lane];
    }
#pragma unroll
    for (int t = 0; t < 10; ++t) {
      int c = oc_t[(size_t)row * 10 + t];
      a1 += 0.9f * ow_t[(size_t)row * 10 + t] * item_emb[(size_t)c * 64 + lane];
    }
  }
  sm[wid][0][lane] = a0;
  sm[wid][1][lane] = a1;
  __syncthreads();
  float y0 = bq1[lane], y1 = bq1[lane];
  for (int k = 0; k < 64; ++k) {
    float w = Wlds[k * 64 + lane];
    y0 += sm[wid][0][k] * w;
    y1 += sm[wid][1][k] * w;
  }
  float wq = wq2[lane];
  float s0 = wred_sum(tanhf(y0) * wq);
  float s1 = wred_sum(tanhf(y1) * wq);
  float mx = fmaxf(s0, s1);
  float e0 = expf(s0 - mx), e1 = expf(s1 - mx);
  float inv = 1.f / (e0 + e1);
  float h = (e0 * inv) * a0 + (e1 * inv) * a1;
  float n2 = wred_sum(h * h);
  float nrm = fmaxf(sqrtf(n2), 1e-12f);
  hn[(size_t)row * 64 + lane] = h / nrm;
}

// ============ L6: ui_prop layer2 + mean + h add (final) ======================
__global__ __launch_bounds__(256) void k_prop2(
    const float* __restrict__ in, const float* __restrict__ ue,
    const float* __restrict__ ie, float* __restrict__ out,
    const int* __restrict__ offs, const int* __restrict__ csr,
    const float* __restrict__ dis, const float* __restrict__ hn)
{
  int tid = threadIdx.x;
  int lane = tid & 63, wid = tid >> 6;
  int row = blockIdx.x * 4 + wid;
  int q = lane >> 3, c8 = lane & 7;
  float4 acc0 = make_float4(0.f, 0.f, 0.f, 0.f);
  float4 acc1 = make_float4(0.f, 0.f, 0.f, 0.f);
  int e0 = offs[row], e1 = offs[row + 1];
  for (int e = e0 + q; e < e1; e += 8) {
    int cc = csr[e];
    const float* src = in + (size_t)cc * 64;
    float4 v0 = *(const float4*)(src + c8 * 8);
    float4 v1 = *(const float4*)(src + c8 * 8 + 4);
    float d = dis[cc];
    acc0.x += d * v0.x; acc0.y += d * v0.y; acc0.z += d * v0.z; acc0.w += d * v0.w;
    acc1.x += d * v1.x; acc1.y += d * v1.y; acc1.z += d * v1.z; acc1.w += d * v1.w;
  }
#pragma unroll
  for (int off = 8; off <= 32; off <<= 1) {
    acc0.x += __shfl_xor(acc0.x, off, 64);
    acc0.y += __shfl_xor(acc0.y, off, 64);
    acc0.z += __shfl_xor(acc0.z, off, 64);
    acc0.w += __shfl_xor(acc0.w, off, 64);
    acc1.x += __shfl_xor(acc1.x, off, 64);
    acc1.y += __shfl_xor(acc1.y, off, 64);
    acc1.z += __shfl_xor(acc1.z, off, 64);
    acc1.w += __shfl_xor(acc1.w, off, 64);
  }
  if (q == 0) {
    float dr = dis[row];
    acc0.x *= dr; acc0.y *= dr; acc0.z *= dr; acc0.w *= dr;
    acc1.x *= dr; acc1.y *= dr; acc1.z *= dr; acc1.w *= dr;
    const float* egop = (row < N_USER) ? ue + (size_t)row * 64
                                       : ie + (size_t)(row - N_USER) * 64;
    float4 eg0 = *(const float4*)(egop + c8 * 8);
    float4 eg1 = *(const float4*)(egop + c8 * 8 + 4);
    float4 l10 = *(const float4*)(in + (size_t)row * 64 + c8 * 8);
    float4 l11 = *(const float4*)(in + (size_t)row * 64 + c8 * 8 + 4);
    float4 o0, o1;
    o0.x = (eg0.x + l10.x + acc0.x) * (1.f / 3.f);
    o0.y = (eg0.y + l10.y + acc0.y) * (1.f / 3.f);
    o0.z = (eg0.z + l10.z + acc0.z) * (1.f / 3.f);
    o0.w = (eg0.w + l10.w + acc0.w) * (1.f / 3.f);
    o1.x = (eg1.x + l11.x + acc1.x) * (1.f / 3.f);
    o1.y = (eg1.y + l11.y + acc1.y) * (1.f / 3.f);
    o1.z = (eg1.z + l11.z + acc1.z) * (1.f / 3.f);
    o1.w = (eg1.w + l11.w + acc1.w) * (1.f / 3.f);
    if (row >= N_USER) {
      const float* hp = hn + (size_t)(row - N_USER) * 64;
      float4 h0 = *(const float4*)(hp + c8 * 8);
      float4 h1 = *(const float4*)(hp + c8 * 8 + 4);
      o0.x += h0.x; o0.y += h0.y; o0.z += h0.z; o0.w += h0.w;
      o1.x += h1.x; o1.y += h1.y; o1.z += h1.z; o1.w += h1.w;
    }
    *(float4*)(out + (size_t)row * 64 + c8 * 8) = o0;
    *(float4*)(out + (size_t)row * 64 + c8 * 8 + 4) = o1;
  }
}

// ---------------- host driver ------------------------------------------------
extern "C" void kernel_launch(void* const* d_in, const int* in_sizes, int n_in,
                              void* d_out, int out_size, void* d_ws, size_t ws_size,
                              hipStream_t stream)
{
  (void)in_sizes; (void)n_in; (void)out_size; (void)ws_size;
  const float* user_emb = (const float*)d_in[0];
  const float* item_emb = (const float*)d_in[1];
  const float* v_feat   = (const float*)d_in[2];
  const float* t_feat   = (const float*)d_in[3];
  const float* W_v      = (const float*)d_in[4];
  const float* b_v      = (const float*)d_in[5];
  const float* W_t      = (const float*)d_in[6];
  const float* b_t      = (const float*)d_in[7];
  const float* Wq1      = (const float*)d_in[8];
  const float* bq1      = (const float*)d_in[9];
  const float* wq2      = (const float*)d_in[10];
  const float* ow_i     = (const float*)d_in[11];
  const float* ow_t     = (const float*)d_in[12];
  const int*   eidx     = (const int*)d_in[13];
  const int*   oc_i     = (const int*)d_in[14];
  const int*   oc_t     = (const int*)d_in[15];
  float* out = (float*)d_out;

  char* wp = (char*)d_ws;
  auto alloc = [&](size_t bytes) -> void* {
    void* p = (void*)wp;
    wp += (bytes + 255) & ~(size_t)255;
    return p;
  };
  // region A: Pp_i (4 x 2.05 MB) -> later pk (2 x 5.12 MB = 10.24 MB)
  size_t pk_bytes = (size_t)2 * N_ITEM * (NJC * 10) * 4;          // 10.24 MB
  char* regionA = (char*)alloc(pk_bytes + 1024);
  // region B: Pp_t (2 x 2.05 MB) -> later E1 (8.19 MB)
  char* regionB = (char*)alloc((size_t)N_NODE * 64 * 4 + 1024);
  float* Pp_i = (float*)regionA;
  float* Pp_t = (float*)regionB;
  unsigned int* pk = (unsigned int*)regionA;    // alive after norm_dual
  float* E1 = (float*)regionB;                  // alive after L3 (sim reads done)

  unsigned short* Xhi = (unsigned short*)alloc((size_t)N_ITEM * 64 * 2);
  unsigned short* Xli = (unsigned short*)alloc((size_t)N_ITEM * 64 * 2);
  unsigned short* Xht = (unsigned short*)alloc((size_t)N_ITEM * 64 * 2);
  unsigned short* Xlt = (unsigned short*)alloc((size_t)N_ITEM * 64 * 2);
  float* tv_i  = (float*)alloc((size_t)N_ITEM * 10 * 4);
  int*   tc_i  = (int*)  alloc((size_t)N_ITEM * 10 * 4);
  float* dis_i = (float*)alloc((size_t)N_ITEM * 4);
  float* tv_t  = (float*)alloc((size_t)N_ITEM * 10 * 4);
  int*   tc_t  = (int*)  alloc((size_t)N_ITEM * 10 * 4);
  float* dis_t = (float*)alloc((size_t)N_ITEM * 4);
  float* hn    = (float*)alloc((size_t)N_ITEM * 64 * 4);
  int*   degcur= (int*)  alloc((size_t)2 * N_NODE * 4);   // degi | curs contiguous
  int*   degi  = degcur;
  int*   curs  = degcur + N_NODE;
  int*   offs  = (int*)  alloc((size_t)(N_NODE + 1) * 4);
  float* disui = (float*)alloc((size_t)N_NODE * 4);
  int*   csr   = (int*)  alloc((size_t)N_EDGE * 4);

  // L0: zero degree + cursor arrays (single async memset, capture-safe)
  hipMemsetAsync(degcur, 0, (size_t)2 * N_NODE * 4, stream);
  // L1: MFMA projections (both modalities) + UI degree count
  k_gemm_count<<<NB_G + 3125, 256, 0, stream>>>(v_feat, W_v, t_feat, W_t, Pp_i, Pp_t,
                                                eidx, degi);
  // L2: normalize + bf16 hi/lo split
  norm_dual<<<dim3(2000, 2), 256, 0, stream>>>(Pp_i, b_v, Xhi, Xli, Pp_t, b_t, Xht, Xlt);
  // L3: scan (block 0, overlapped) + sim + topk (both modalities)
  k_sim_scan<<<NB_SIM + 1, 256, 0, stream>>>(Xhi, Xli, Xht, Xlt, pk, degi, offs, disui);
  // L4: merge candidates -> top10/dis + CSR fill
  k_merge_fill<<<NB_M + 3125, 256, 0, stream>>>(pk, tv_i, tc_i, dis_i, tv_t, tc_t, dis_t,
                                                eidx, eidx + N_EDGE, offs, curs, csr);
  // L5: fused SPMM+attention+h_norm + UI propagation layer 1
  k_spmm_prop1<<<NB_S + 8000, 256, 0, stream>>>(tv_i, tc_i, dis_i, ow_i, oc_i,
                                                tv_t, tc_t, dis_t, ow_t, oc_t,
                                                item_emb, Wq1, bq1, wq2, hn,
                                                user_emb, E1, offs, csr, disui);
  // L6: UI propagation layer 2 + mean + h_norm add
  k_prop2<<<8000, 256, 0, stream>>>(E1, user_emb, item_emb, out, offs, csr, disui, hn);
}